// Round 1
// baseline (1135.765 us; speedup 1.0000x reference)
//
#include <hip/hip_runtime.h>
#include <math.h>

#define D 256
#define NC 8
#define G 16
#define MINS 10
#define CS 512

// ---- workspace layout (bytes) ----
#define OFF_CNT     0u
#define OFF_CUR     64u
#define OFF_OFFS    128u
#define OFF_LOGDET  256u
#define OFF_IDX     1024u
#define OFF_RNORM   (OFF_IDX + 65536u*4u)          // 263,168
#define OFF_GRAM    (1u<<20)                        // 1 MB
#define GRAM_BYTES  (G*D*D*4u)                      // 4 MB
#define OFF_PART    (OFF_GRAM + GRAM_BYTES)         // 5 MB

__global__ void k_init(int* counts) {
    if (threadIdx.x < G) counts[threadIdx.x] = 0;
}

__global__ void k_norm(const float* __restrict__ feat, float* __restrict__ rnorm, int n) {
    int row = blockIdx.x * 4 + (threadIdx.x >> 6);
    if (row >= n) return;
    int lane = threadIdx.x & 63;
    const float4 v = *(const float4*)(feat + (size_t)row * D + lane * 4);
    float s = v.x*v.x + v.y*v.y + v.z*v.z + v.w*v.w;
    #pragma unroll
    for (int d = 32; d; d >>= 1) s += __shfl_xor(s, d, 64);
    if (lane == 0) rnorm[row] = 1.0f / fmaxf(sqrtf(s), 1e-12f);
}

__device__ __forceinline__ int group_of(int t, int b) {
    t = t < 0 ? 0 : (t > NC - 1 ? NC - 1 : t);
    return b * NC + t;
}

__global__ void k_count(const int* __restrict__ target, const int* __restrict__ batch,
                        int* counts, int n) {
    __shared__ int h[G];
    if (threadIdx.x < G) h[threadIdx.x] = 0;
    __syncthreads();
    for (int i = blockIdx.x * blockDim.x + threadIdx.x; i < n; i += gridDim.x * blockDim.x)
        atomicAdd(&h[group_of(target[i], batch[i])], 1);
    __syncthreads();
    if (threadIdx.x < G) atomicAdd(&counts[threadIdx.x], h[threadIdx.x]);
}

__global__ void k_prefix(const int* __restrict__ counts, int* offs, int* cur) {
    if (threadIdx.x == 0) {
        int o = 0;
        for (int g = 0; g < G; ++g) { offs[g] = o; cur[g] = o; o += counts[g]; }
    }
}

__global__ void k_scatter(const int* __restrict__ target, const int* __restrict__ batch,
                          int* cur, int* __restrict__ idxbuf, int n) {
    for (int i = blockIdx.x * blockDim.x + threadIdx.x; i < n; i += gridDim.x * blockDim.x) {
        int g = group_of(target[i], batch[i]);
        int pos = atomicAdd(&cur[g], 1);
        idxbuf[pos] = i;
    }
}

// grouped split-K SYRK: partial[slot][g] += Z_chunk^T Z_chunk (128x128 tiles)
// blockIdx.x = tilepair p in {0:(0,0), 1:(1,0), 2:(1,1)}; y = group; z = K-slot
__global__ __launch_bounds__(256) void k_gram(
    const float* __restrict__ feat, const float* __restrict__ rnorm,
    const int* __restrict__ idxbuf, const int* __restrict__ counts,
    const int* __restrict__ offs, float* __restrict__ part) {
    const int p  = blockIdx.x;
    const int g  = blockIdx.y;
    const int slot = blockIdx.z;
    const int CH = gridDim.z;
    const int ti = (p >= 1) ? 1 : 0, tj = (p == 2) ? 1 : 0;
    const int n = counts[g], off = offs[g];

    __shared__ float LA[32][132];
    __shared__ float LB[32][132];

    const int tid = threadIdx.x;
    const int ty = tid >> 4, tx = tid & 15;   // compute mapping
    const int rr = tid >> 3, seg = tid & 7;   // staging mapping

    float acc[8][8];
    #pragma unroll
    for (int i = 0; i < 8; ++i)
        #pragma unroll
        for (int j = 0; j < 8; ++j) acc[i][j] = 0.0f;

    for (int c = slot; c * CS < n; c += CH) {
        const int cbase = c * CS;
        const int cend  = (cbase + CS < n) ? cbase + CS : n;
        for (int sub = cbase; sub < cend; sub += 32) {
            // ---- load 32 rows x slice(s) into registers ----
            const int r = sub + rr;
            const bool valid = (r < cend);
            const int row = valid ? idxbuf[off + r] : 0;
            const float inv = valid ? rnorm[row] : 0.0f;
            const float* bA = feat + (size_t)row * D + ti * 128 + seg * 16;
            float4 va[4], vb[4];
            #pragma unroll
            for (int q = 0; q < 4; ++q) {
                float4 v = *(const float4*)(bA + q * 4);
                v.x *= inv; v.y *= inv; v.z *= inv; v.w *= inv;
                va[q] = v;
            }
            if (p == 1) {
                const float* bB = feat + (size_t)row * D + seg * 16;  // tj=0 slice
                #pragma unroll
                for (int q = 0; q < 4; ++q) {
                    float4 v = *(const float4*)(bB + q * 4);
                    v.x *= inv; v.y *= inv; v.z *= inv; v.w *= inv;
                    vb[q] = v;
                }
            }
            __syncthreads();  // previous compute done before overwriting LDS
            #pragma unroll
            for (int q = 0; q < 4; ++q)
                *(float4*)&LA[rr][seg * 16 + q * 4] = va[q];
            if (p == 1) {
                #pragma unroll
                for (int q = 0; q < 4; ++q)
                    *(float4*)&LB[rr][seg * 16 + q * 4] = vb[q];
            }
            __syncthreads();

            // ---- 128x128 outer-product accumulate over 32 rows ----
            const float (*Bt)[132] = (p == 1) ? LB : LA;
            #pragma unroll 4
            for (int r2 = 0; r2 < 32; ++r2) {
                const float* Ar = &LA[r2][0];
                const float* Br = &Bt[r2][0];
                float4 a0 = *(const float4*)(Ar + ty * 8);
                float4 a1 = *(const float4*)(Ar + ty * 8 + 4);
                float4 b0 = *(const float4*)(Br + tx * 4);
                float4 b1 = *(const float4*)(Br + 64 + tx * 4);
                float av[8] = {a0.x,a0.y,a0.z,a0.w,a1.x,a1.y,a1.z,a1.w};
                float bv[8] = {b0.x,b0.y,b0.z,b0.w,b1.x,b1.y,b1.z,b1.w};
                #pragma unroll
                for (int i = 0; i < 8; ++i)
                    #pragma unroll
                    for (int j = 0; j < 8; ++j)
                        acc[i][j] = fmaf(av[i], bv[j], acc[i][j]);
            }
        }
    }

    // ---- write this slot's partial tile (plain stores, disjoint) ----
    float* base = part + ((size_t)slot * G + g) * (D * D);
    #pragma unroll
    for (int i = 0; i < 8; ++i) {
        const int row_g = ti * 128 + ty * 8 + i;
        float4 lo = {acc[i][0], acc[i][1], acc[i][2], acc[i][3]};
        float4 hi = {acc[i][4], acc[i][5], acc[i][6], acc[i][7]};
        *(float4*)(base + (size_t)row_g * D + tj * 128 + tx * 4)      = lo;
        *(float4*)(base + (size_t)row_g * D + tj * 128 + 64 + tx * 4) = hi;
    }
    if (p == 1) {  // mirror (1,0) into (0,1)
        #pragma unroll
        for (int j = 0; j < 8; ++j) {
            const int col_g = (j < 4) ? (tx * 4 + j) : (64 + tx * 4 + (j - 4));
            float4 lo = {acc[0][j], acc[1][j], acc[2][j], acc[3][j]};
            float4 hi = {acc[4][j], acc[5][j], acc[6][j], acc[7][j]};
            float* dst = base + (size_t)col_g * D + 128 + ty * 8;
            *(float4*)dst       = lo;
            *(float4*)(dst + 4) = hi;
        }
    }
}

__global__ void k_reduce(const float* __restrict__ part, float* __restrict__ gram, int CH) {
    const int total4 = G * D * D / 4;
    const float4* p4 = (const float4*)part;
    float4* g4 = (float4*)gram;
    for (int e = blockIdx.x * blockDim.x + threadIdx.x; e < total4; e += gridDim.x * blockDim.x) {
        float4 s = p4[e];
        for (int ch = 1; ch < CH; ++ch) {
            float4 t = p4[(size_t)ch * total4 + e];
            s.x += t.x; s.y += t.y; s.z += t.z; s.w += t.w;
        }
        g4[e] = s;
    }
}

// packed-lower-triangle row offset, rows padded to 4 floats
__device__ __forceinline__ int rowoff(int i) {
    int q = i >> 2, s = i & 3;
    return 4 * (2 * q * (q + 1) + s * (q + 1));
}

// one block per group: in-LDS right-looking Cholesky, logdet = sum log(pivots)
__global__ __launch_bounds__(256) void k_chol(
    const float* __restrict__ gram, const int* __restrict__ counts,
    float* __restrict__ logdetbuf) {
    const int g = blockIdx.x;
    const int tid = threadIdx.x;
    __shared__ float T[33280];      // 130 KB packed lower triangle (padded rows)
    __shared__ float colbuf[256];

    const int n = counts[g];
    const float nn = fmaxf((float)n, 1.0f);
    const float a = (float)D / (nn * 0.04f);   // D / (n * eps^2), eps=0.2

    // load M = a*gram + (1+1e-6) I  (one row per thread)
    {
        const int i = tid;
        const float* Gr = gram + ((size_t)g * D * D) + (size_t)i * D;
        float* Tr = T + rowoff(i);
        for (int j = 0; j < i; ++j) Tr[j] = a * Gr[j];
        Tr[i] = a * Gr[i] + 1.0f + 1e-6f;
    }
    __syncthreads();

    float ld = 0.0f;
    for (int k = 0; k < D; ++k) {
        const float akk = T[rowoff(k) + k];
        ld += logf(akk);
        const float inv = 1.0f / sqrtf(akk);
        const int i = k + 1 + tid;
        if (i < D) colbuf[i] = T[rowoff(i) + k] * inv;
        __syncthreads();
        if (i < D) {
            const float ci = colbuf[i];
            float* Tr = T + rowoff(i);
            int j = k + 1;
            for (; j <= i && (j & 3); ++j) Tr[j] -= ci * colbuf[j];
            for (; j + 3 <= i; j += 4) {
                float4 t = *(float4*)&Tr[j];
                const float4 c = *(const float4*)&colbuf[j];
                t.x -= ci * c.x; t.y -= ci * c.y; t.z -= ci * c.z; t.w -= ci * c.w;
                *(float4*)&Tr[j] = t;
            }
            for (; j <= i; ++j) Tr[j] -= ci * colbuf[j];
        }
        __syncthreads();
    }
    if (tid == 0) logdetbuf[g] = ld;
}

__global__ void k_final(const float* __restrict__ ld, const int* __restrict__ counts,
                        float* __restrict__ out) {
    if (threadIdx.x == 0 && blockIdx.x == 0) {
        const float min_tcr = 0.5f * logf(256.0f);
        const float log_diag = logf(1.0f + 1e-6f + 1e-12f);
        float s[2] = {0.0f, 0.0f}, c2[2] = {0.0f, 0.0f};
        for (int g = 0; g < G; ++g) {
            const float n = (float)counts[g];
            const float nn = fmaxf(n, 1.0f);
            const float logdet = ld[g] + (nn - (float)D) * log_diag;
            const float tcr = 0.5f * logdet;
            const float def = fmaxf(min_tcr - tcr, 0.0f);
            if (counts[g] >= MINS) { s[g / NC] += def; c2[g / NC] += 1.0f; }
        }
        float avg = 0.0f;
        for (int b = 0; b < 2; ++b)
            avg += (c2[b] > 0.0f) ? s[b] / fmaxf(c2[b], 1.0f) : 0.0f;
        avg *= 0.5f;                 // mean over B=2 scenes
        out[0] = 1.0f * 0.05f * avg; // loss_weight * lambda_tcr * avg
    }
}

extern "C" void kernel_launch(void* const* d_in, const int* in_sizes, int n_in,
                              void* d_out, int out_size, void* d_ws, size_t ws_size,
                              hipStream_t stream) {
    const int*   target = (const int*)d_in[1];
    const float* feat   = (const float*)d_in[2];
    const int*   batch  = (const int*)d_in[3];
    float* out = (float*)d_out;
    char* ws = (char*)d_ws;
    const int n = in_sizes[1];   // 65536 points

    int*   counts = (int*)(ws + OFF_CNT);
    int*   cur    = (int*)(ws + OFF_CUR);
    int*   offs   = (int*)(ws + OFF_OFFS);
    float* logdet = (float*)(ws + OFF_LOGDET);
    int*   idxbuf = (int*)(ws + OFF_IDX);
    float* rnorm  = (float*)(ws + OFF_RNORM);
    float* gram   = (float*)(ws + OFF_GRAM);

    // split-K depth adapted to workspace size (each K-slot partial = 4 MB)
    long avail = (long)ws_size - (long)OFF_PART;
    int CH;
    float* part;
    bool need_reduce;
    if (avail >= (long)GRAM_BYTES) {
        long c = avail / (long)GRAM_BYTES;
        CH = (int)(c < 8 ? c : 8);
        part = (float*)(ws + OFF_PART);
        need_reduce = true;
    } else {
        CH = 1;
        part = gram;          // write gram directly, skip reduce
        need_reduce = false;
    }

    k_init   <<<1, 64, 0, stream>>>(counts);
    k_norm   <<<(n + 3) / 4, 256, 0, stream>>>(feat, rnorm, n);
    k_count  <<<256, 256, 0, stream>>>(target, batch, counts, n);
    k_prefix <<<1, 64, 0, stream>>>(counts, offs, cur);
    k_scatter<<<256, 256, 0, stream>>>(target, batch, cur, idxbuf, n);
    k_gram   <<<dim3(3, G, CH), 256, 0, stream>>>(feat, rnorm, idxbuf, counts, offs, part);
    if (need_reduce)
        k_reduce<<<256, 256, 0, stream>>>(part, gram, CH);
    k_chol   <<<G, 256, 0, stream>>>(gram, counts, logdet);
    k_final  <<<1, 64, 0, stream>>>(logdet, counts, out);
}

// Round 2
// 545.905 us; speedup vs baseline: 2.0805x; 2.0805x over previous
//
#include <hip/hip_runtime.h>
#include <math.h>

#define D 256
#define NC 8
#define G 16
#define MINS 10
#define CS 512

// ---- workspace layout (bytes) ----
#define OFF_CNT     0u
#define OFF_CUR     64u
#define OFF_OFFS    128u
#define OFF_LOGDET  256u
#define OFF_IDX     1024u
#define OFF_RNORM   (OFF_IDX + 65536u*4u)          // 263,168
#define OFF_GRAM    (1u<<20)                        // 1 MB
#define GRAM_BYTES  (G*D*D*4u)                      // 4 MB
#define OFF_PART    (OFF_GRAM + GRAM_BYTES)         // 5 MB

__global__ void k_init(int* counts) {
    if (threadIdx.x < G) counts[threadIdx.x] = 0;
}

__global__ void k_norm(const float* __restrict__ feat, float* __restrict__ rnorm, int n) {
    int row = blockIdx.x * 4 + (threadIdx.x >> 6);
    if (row >= n) return;
    int lane = threadIdx.x & 63;
    const float4 v = *(const float4*)(feat + (size_t)row * D + lane * 4);
    float s = v.x*v.x + v.y*v.y + v.z*v.z + v.w*v.w;
    #pragma unroll
    for (int d = 32; d; d >>= 1) s += __shfl_xor(s, d, 64);
    if (lane == 0) rnorm[row] = 1.0f / fmaxf(sqrtf(s), 1e-12f);
}

__device__ __forceinline__ int group_of(int t, int b) {
    t = t < 0 ? 0 : (t > NC - 1 ? NC - 1 : t);
    return b * NC + t;
}

__global__ void k_count(const int* __restrict__ target, const int* __restrict__ batch,
                        int* counts, int n) {
    __shared__ int h[G];
    if (threadIdx.x < G) h[threadIdx.x] = 0;
    __syncthreads();
    for (int i = blockIdx.x * blockDim.x + threadIdx.x; i < n; i += gridDim.x * blockDim.x)
        atomicAdd(&h[group_of(target[i], batch[i])], 1);
    __syncthreads();
    if (threadIdx.x < G) atomicAdd(&counts[threadIdx.x], h[threadIdx.x]);
}

__global__ void k_prefix(const int* __restrict__ counts, int* offs, int* cur) {
    if (threadIdx.x == 0) {
        int o = 0;
        for (int g = 0; g < G; ++g) { offs[g] = o; cur[g] = o; o += counts[g]; }
    }
}

__global__ void k_scatter(const int* __restrict__ target, const int* __restrict__ batch,
                          int* cur, int* __restrict__ idxbuf, int n) {
    for (int i = blockIdx.x * blockDim.x + threadIdx.x; i < n; i += gridDim.x * blockDim.x) {
        int g = group_of(target[i], batch[i]);
        int pos = atomicAdd(&cur[g], 1);
        idxbuf[pos] = i;
    }
}

// grouped split-K SYRK: partial[slot][g] += Z_chunk^T Z_chunk (128x128 tiles)
__global__ __launch_bounds__(256) void k_gram(
    const float* __restrict__ feat, const float* __restrict__ rnorm,
    const int* __restrict__ idxbuf, const int* __restrict__ counts,
    const int* __restrict__ offs, float* __restrict__ part) {
    const int p  = blockIdx.x;
    const int g  = blockIdx.y;
    const int slot = blockIdx.z;
    const int CH = gridDim.z;
    const int ti = (p >= 1) ? 1 : 0, tj = (p == 2) ? 1 : 0;
    const int n = counts[g], off = offs[g];

    __shared__ float LA[32][132];
    __shared__ float LB[32][132];

    const int tid = threadIdx.x;
    const int ty = tid >> 4, tx = tid & 15;
    const int rr = tid >> 3, seg = tid & 7;

    float acc[8][8];
    #pragma unroll
    for (int i = 0; i < 8; ++i)
        #pragma unroll
        for (int j = 0; j < 8; ++j) acc[i][j] = 0.0f;

    for (int c = slot; c * CS < n; c += CH) {
        const int cbase = c * CS;
        const int cend  = (cbase + CS < n) ? cbase + CS : n;
        for (int sub = cbase; sub < cend; sub += 32) {
            const int r = sub + rr;
            const bool valid = (r < cend);
            const int row = valid ? idxbuf[off + r] : 0;
            const float inv = valid ? rnorm[row] : 0.0f;
            const float* bA = feat + (size_t)row * D + ti * 128 + seg * 16;
            float4 va[4], vb[4];
            #pragma unroll
            for (int q = 0; q < 4; ++q) {
                float4 v = *(const float4*)(bA + q * 4);
                v.x *= inv; v.y *= inv; v.z *= inv; v.w *= inv;
                va[q] = v;
            }
            if (p == 1) {
                const float* bB = feat + (size_t)row * D + seg * 16;
                #pragma unroll
                for (int q = 0; q < 4; ++q) {
                    float4 v = *(const float4*)(bB + q * 4);
                    v.x *= inv; v.y *= inv; v.z *= inv; v.w *= inv;
                    vb[q] = v;
                }
            }
            __syncthreads();
            #pragma unroll
            for (int q = 0; q < 4; ++q)
                *(float4*)&LA[rr][seg * 16 + q * 4] = va[q];
            if (p == 1) {
                #pragma unroll
                for (int q = 0; q < 4; ++q)
                    *(float4*)&LB[rr][seg * 16 + q * 4] = vb[q];
            }
            __syncthreads();

            const float (*Bt)[132] = (p == 1) ? LB : LA;
            #pragma unroll 4
            for (int r2 = 0; r2 < 32; ++r2) {
                const float* Ar = &LA[r2][0];
                const float* Br = &Bt[r2][0];
                float4 a0 = *(const float4*)(Ar + ty * 8);
                float4 a1 = *(const float4*)(Ar + ty * 8 + 4);
                float4 b0 = *(const float4*)(Br + tx * 4);
                float4 b1 = *(const float4*)(Br + 64 + tx * 4);
                float av[8] = {a0.x,a0.y,a0.z,a0.w,a1.x,a1.y,a1.z,a1.w};
                float bv[8] = {b0.x,b0.y,b0.z,b0.w,b1.x,b1.y,b1.z,b1.w};
                #pragma unroll
                for (int i = 0; i < 8; ++i)
                    #pragma unroll
                    for (int j = 0; j < 8; ++j)
                        acc[i][j] = fmaf(av[i], bv[j], acc[i][j]);
            }
        }
    }

    float* base = part + ((size_t)slot * G + g) * (D * D);
    #pragma unroll
    for (int i = 0; i < 8; ++i) {
        const int row_g = ti * 128 + ty * 8 + i;
        float4 lo = {acc[i][0], acc[i][1], acc[i][2], acc[i][3]};
        float4 hi = {acc[i][4], acc[i][5], acc[i][6], acc[i][7]};
        *(float4*)(base + (size_t)row_g * D + tj * 128 + tx * 4)      = lo;
        *(float4*)(base + (size_t)row_g * D + tj * 128 + 64 + tx * 4) = hi;
    }
    if (p == 1) {
        #pragma unroll
        for (int j = 0; j < 8; ++j) {
            const int col_g = (j < 4) ? (tx * 4 + j) : (64 + tx * 4 + (j - 4));
            float4 lo = {acc[0][j], acc[1][j], acc[2][j], acc[3][j]};
            float4 hi = {acc[4][j], acc[5][j], acc[6][j], acc[7][j]};
            float* dst = base + (size_t)col_g * D + 128 + ty * 8;
            *(float4*)dst       = lo;
            *(float4*)(dst + 4) = hi;
        }
    }
}

__global__ void k_reduce(const float* __restrict__ part, float* __restrict__ gram, int CH) {
    const int total4 = G * D * D / 4;
    const float4* p4 = (const float4*)part;
    float4* g4 = (float4*)gram;
    for (int e = blockIdx.x * blockDim.x + threadIdx.x; e < total4; e += gridDim.x * blockDim.x) {
        float4 s = p4[e];
        for (int ch = 1; ch < CH; ++ch) {
            float4 t = p4[(size_t)ch * total4 + e];
            s.x += t.x; s.y += t.y; s.z += t.z; s.w += t.w;
        }
        g4[e] = s;
    }
}

// packed-lower-triangle row offset, rows padded to 4 floats
__device__ __forceinline__ int rowoff(int i) {
    int q = i >> 2, s = i & 3;
    return 4 * (2 * q * (q + 1) + s * (q + 1));
}

// one block per group: blocked (BK=16) in-LDS Cholesky, logdet = sum log(pivots)
// Phase A: 16x16 diag factor in registers (lanes 0-15, shfl broadcasts)
// Phase B: TRSM one row/thread, panel written TRANSPOSED to PT
// Phase C: trailing SYRK, 32x32 macro-tile per wave, 4x4 regs per lane
__global__ __launch_bounds__(512) void k_chol(
    const float* __restrict__ gram, const int* __restrict__ counts,
    float* __restrict__ logdetbuf) {
    const int g = blockIdx.x;
    const int tid = threadIdx.x;
    __shared__ float T[33280];        // 130 KB packed lower triangle
    __shared__ float PT[16 * 256];    // 16 KB transposed panel
    __shared__ float L11b[16][16];
    __shared__ float invdb[16];

    const int n = counts[g];
    const float nn = fmaxf((float)n, 1.0f);
    const float aa = (float)D / (nn * 0.04f);   // D / (n * eps^2)
    const float dg = 1.0f + 1e-6f;

    // ---- load M = a*gram + (1+1e-6)I into packed triangle (2 threads/row) ----
    {
        const int r = tid >> 1, half = tid & 1;
        const int nch = (r >> 2) + 1;
        const int mid = (nch + 1) >> 1;
        const int clo = half ? mid : 0;
        const int chi = half ? nch : mid;
        const float* Gr = gram + (size_t)g * (D * D) + (size_t)r * D;
        float* Tr = T + rowoff(r);
        for (int c = clo; c < chi; ++c) {
            float4 v = *(const float4*)(Gr + c * 4);
            v.x *= aa; v.y *= aa; v.z *= aa; v.w *= aa;
            v.x += (c * 4 + 0 == r) ? dg : 0.0f;
            v.y += (c * 4 + 1 == r) ? dg : 0.0f;
            v.z += (c * 4 + 2 == r) ? dg : 0.0f;
            v.w += (c * 4 + 3 == r) ? dg : 0.0f;
            *(float4*)(Tr + c * 4) = v;
        }
    }
    __syncthreads();

    float ldacc = 0.0f;

    for (int kb = 0; kb < 16; ++kb) {
        const int kb16 = kb * 16;

        // ---- A: diagonal block factor (lanes 0-15, register rows) ----
        if (tid < 16) {
            const int lane = tid;
            const int r = kb16 + lane;
            float rr[16];
            const float* Tr = T + rowoff(r);
            #pragma unroll
            for (int q = 0; q < 4; ++q) {
                if (kb16 + q * 4 <= r) {
                    float4 v = *(const float4*)(Tr + kb16 + q * 4);
                    rr[q*4+0] = v.x; rr[q*4+1] = v.y; rr[q*4+2] = v.z; rr[q*4+3] = v.w;
                } else {
                    rr[q*4+0] = 0.0f; rr[q*4+1] = 0.0f; rr[q*4+2] = 0.0f; rr[q*4+3] = 0.0f;
                }
            }
            #pragma unroll
            for (int pc = 0; pc < 16; ++pc) {
                const float piv = __shfl(rr[pc], pc);
                ldacc += logf(piv);                 // identical on all lanes; lane0's used
                const float inv = 1.0f / sqrtf(piv);
                if (lane == 0) invdb[pc] = inv;
                if (lane > pc) rr[pc] *= inv;       // L[lane][pc]
                #pragma unroll
                for (int j = pc + 1; j < 16; ++j) {
                    const float Lj = __shfl(rr[pc], j);
                    if (lane >= j) rr[j] -= rr[pc] * Lj;
                }
            }
            #pragma unroll
            for (int pp = 0; pp < 16; ++pp)
                if (pp < lane) L11b[lane][pp] = rr[pp];
        }
        __syncthreads();

        const int pstart = kb16 + 16;
        const int R = 256 - pstart;

        // ---- B: TRSM, one row per thread; write panel transposed ----
        if (tid < R) {
            const int r = pstart + tid;
            const float* Tr = T + rowoff(r) + kb16;
            float x[16];
            {
                float4 v0 = *(const float4*)(Tr + 0);
                float4 v1 = *(const float4*)(Tr + 4);
                float4 v2 = *(const float4*)(Tr + 8);
                float4 v3 = *(const float4*)(Tr + 12);
                x[0]=v0.x; x[1]=v0.y; x[2]=v0.z; x[3]=v0.w;
                x[4]=v1.x; x[5]=v1.y; x[6]=v1.z; x[7]=v1.w;
                x[8]=v2.x; x[9]=v2.y; x[10]=v2.z; x[11]=v2.w;
                x[12]=v3.x; x[13]=v3.y; x[14]=v3.z; x[15]=v3.w;
            }
            #pragma unroll
            for (int c = 0; c < 16; ++c) {
                float Lr[16];
                {
                    float4 L0 = *(const float4*)&L11b[c][0];
                    float4 L1 = *(const float4*)&L11b[c][4];
                    float4 L2 = *(const float4*)&L11b[c][8];
                    float4 L3 = *(const float4*)&L11b[c][12];
                    Lr[0]=L0.x; Lr[1]=L0.y; Lr[2]=L0.z; Lr[3]=L0.w;
                    Lr[4]=L1.x; Lr[5]=L1.y; Lr[6]=L1.z; Lr[7]=L1.w;
                    Lr[8]=L2.x; Lr[9]=L2.y; Lr[10]=L2.z; Lr[11]=L2.w;
                    Lr[12]=L3.x; Lr[13]=L3.y; Lr[14]=L3.z; Lr[15]=L3.w;
                }
                float s = x[c];
                #pragma unroll
                for (int pp = 0; pp < 16; ++pp)
                    if (pp < c) s -= x[pp] * Lr[pp];
                x[c] = s * invdb[c];
            }
            #pragma unroll
            for (int pp = 0; pp < 16; ++pp)
                PT[pp * 256 + r] = x[pp];
        }
        __syncthreads();

        // ---- C: trailing SYRK update, 32x32 macro per wave, 4x4 per lane ----
        if (R > 0) {
            const int MRm = (R + 31) >> 5;
            const int nmac = MRm * (MRm + 1) / 2;
            const int wave = tid >> 6;
            const int lane = tid & 63;
            const int li = lane >> 3, lj = lane & 7;
            for (int idx = wave; idx < nmac; idx += 8) {
                int MI = 0, base = 0;
                while (base + MI + 1 <= idx) { base += MI + 1; MI++; }
                const int MJ = idx - base;
                const int r0 = pstart + MI * 32 + li * 4;
                const int c0 = pstart + MJ * 32 + lj * 4;
                if (r0 >= 256 || c0 >= 256) continue;
                if (c0 > r0 + 3) continue;

                float acc[4][4];
                #pragma unroll
                for (int qi = 0; qi < 4; ++qi)
                    #pragma unroll
                    for (int qj = 0; qj < 4; ++qj) acc[qi][qj] = 0.0f;

                #pragma unroll
                for (int pp = 0; pp < 16; ++pp) {
                    const float4 av = *(const float4*)&PT[pp * 256 + r0];
                    const float4 bv = *(const float4*)&PT[pp * 256 + c0];
                    float a4[4] = {av.x, av.y, av.z, av.w};
                    float b4[4] = {bv.x, bv.y, bv.z, bv.w};
                    #pragma unroll
                    for (int qi = 0; qi < 4; ++qi)
                        #pragma unroll
                        for (int qj = 0; qj < 4; ++qj)
                            acc[qi][qj] = fmaf(a4[qi], b4[qj], acc[qi][qj]);
                }

                #pragma unroll
                for (int qi = 0; qi < 4; ++qi) {
                    const int r = r0 + qi;
                    float* cp = T + rowoff(r) + c0;
                    if (c0 + 3 <= r) {
                        float4 t = *(float4*)cp;
                        t.x -= acc[qi][0]; t.y -= acc[qi][1];
                        t.z -= acc[qi][2]; t.w -= acc[qi][3];
                        *(float4*)cp = t;
                    } else {
                        #pragma unroll
                        for (int qj = 0; qj < 4; ++qj)
                            if (c0 + qj <= r) cp[qj] -= acc[qi][qj];
                    }
                }
            }
        }
        __syncthreads();
    }

    if (tid == 0) logdetbuf[g] = ldacc;
}

__global__ void k_final(const float* __restrict__ ld, const int* __restrict__ counts,
                        float* __restrict__ out) {
    if (threadIdx.x == 0 && blockIdx.x == 0) {
        const float min_tcr = 0.5f * logf(256.0f);
        const float log_diag = logf(1.0f + 1e-6f + 1e-12f);
        float s[2] = {0.0f, 0.0f}, c2[2] = {0.0f, 0.0f};
        for (int g = 0; g < G; ++g) {
            const float n = (float)counts[g];
            const float nn = fmaxf(n, 1.0f);
            const float logdet = ld[g] + (nn - (float)D) * log_diag;
            const float tcr = 0.5f * logdet;
            const float def = fmaxf(min_tcr - tcr, 0.0f);
            if (counts[g] >= MINS) { s[g / NC] += def; c2[g / NC] += 1.0f; }
        }
        float avg = 0.0f;
        for (int b = 0; b < 2; ++b)
            avg += (c2[b] > 0.0f) ? s[b] / fmaxf(c2[b], 1.0f) : 0.0f;
        avg *= 0.5f;
        out[0] = 1.0f * 0.05f * avg;
    }
}

extern "C" void kernel_launch(void* const* d_in, const int* in_sizes, int n_in,
                              void* d_out, int out_size, void* d_ws, size_t ws_size,
                              hipStream_t stream) {
    const int*   target = (const int*)d_in[1];
    const float* feat   = (const float*)d_in[2];
    const int*   batch  = (const int*)d_in[3];
    float* out = (float*)d_out;
    char* ws = (char*)d_ws;
    const int n = in_sizes[1];

    int*   counts = (int*)(ws + OFF_CNT);
    int*   cur    = (int*)(ws + OFF_CUR);
    int*   offs   = (int*)(ws + OFF_OFFS);
    float* logdet = (float*)(ws + OFF_LOGDET);
    int*   idxbuf = (int*)(ws + OFF_IDX);
    float* rnorm  = (float*)(ws + OFF_RNORM);
    float* gram   = (float*)(ws + OFF_GRAM);

    long avail = (long)ws_size - (long)OFF_PART;
    int CH;
    float* part;
    bool need_reduce;
    if (avail >= (long)GRAM_BYTES) {
        long c = avail / (long)GRAM_BYTES;
        CH = (int)(c < 8 ? c : 8);
        part = (float*)(ws + OFF_PART);
        need_reduce = true;
    } else {
        CH = 1;
        part = gram;
        need_reduce = false;
    }

    k_init   <<<1, 64, 0, stream>>>(counts);
    k_norm   <<<(n + 3) / 4, 256, 0, stream>>>(feat, rnorm, n);
    k_count  <<<256, 256, 0, stream>>>(target, batch, counts, n);
    k_prefix <<<1, 64, 0, stream>>>(counts, offs, cur);
    k_scatter<<<256, 256, 0, stream>>>(target, batch, cur, idxbuf, n);
    k_gram   <<<dim3(3, G, CH), 256, 0, stream>>>(feat, rnorm, idxbuf, counts, offs, part);
    if (need_reduce)
        k_reduce<<<256, 256, 0, stream>>>(part, gram, CH);
    k_chol   <<<G, 512, 0, stream>>>(gram, counts, logdet);
    k_final  <<<1, 64, 0, stream>>>(logdet, counts, out);
}

// Round 3
// 296.192 us; speedup vs baseline: 3.8346x; 1.8431x over previous
//
#include <hip/hip_runtime.h>
#include <math.h>

#define D 256
#define NC 8
#define G 16
#define MINS 10
#define CS 512

// ---- workspace layout (bytes) ----
#define OFF_CNT     0u
#define OFF_OFFS    128u
#define OFF_LOGDET  256u
#define OFF_HIST    1024u                           // NB*16 ints (NB<=256 -> 16KB)
#define OFF_IDX     20480u
#define OFF_RNORM   (OFF_IDX + 65536u*4u)           // 282,624
#define OFF_GRAM    (1u<<20)                         // 1 MB
#define GRAM_BYTES  (G*D*D*4u)                       // 4 MB
#define OFF_PART    (OFF_GRAM + GRAM_BYTES)          // 5 MB

__global__ void k_norm(const float* __restrict__ feat, float* __restrict__ rnorm, int n) {
    int row = blockIdx.x * 4 + (threadIdx.x >> 6);
    if (row >= n) return;
    int lane = threadIdx.x & 63;
    const float4 v = *(const float4*)(feat + (size_t)row * D + lane * 4);
    float s = v.x*v.x + v.y*v.y + v.z*v.z + v.w*v.w;
    #pragma unroll
    for (int d = 32; d; d >>= 1) s += __shfl_xor(s, d, 64);
    if (lane == 0) rnorm[row] = 1.0f / fmaxf(sqrtf(s), 1e-12f);
}

__device__ __forceinline__ int group_of(int t, int b) {
    t = t < 0 ? 0 : (t > NC - 1 ? NC - 1 : t);
    return b * NC + t;
}

// ---- pass 1: per-block 16-bin histogram via ballots (no atomics) ----
__global__ __launch_bounds__(256) void k_hist(
    const int* __restrict__ target, const int* __restrict__ batch,
    int* __restrict__ hist, int n) {
    __shared__ unsigned short wcnt[4][G];
    const int tid = threadIdx.x;
    const int i = blockIdx.x * 256 + tid;
    const int wave = tid >> 6, lane = tid & 63;
    const bool valid = i < n;
    const int g = valid ? group_of(target[i], batch[i]) : -1;
    #pragma unroll
    for (int gv = 0; gv < G; ++gv) {
        unsigned long long m = __ballot(g == gv);
        if (lane == 0) wcnt[wave][gv] = (unsigned short)__popcll(m);
    }
    __syncthreads();
    if (tid < G)
        hist[blockIdx.x * G + tid] =
            (int)wcnt[0][tid] + wcnt[1][tid] + wcnt[2][tid] + wcnt[3][tid];
}

// ---- pass 2: exclusive prefix over blocks per group + group offsets ----
// writes base[blk][g] = offs[g] + sum_{b<blk} hist[b][g]; counts & offs too.
__global__ __launch_bounds__(256) void k_prefix2(
    int* __restrict__ hist, int* __restrict__ counts, int* __restrict__ offs, int NB) {
    __shared__ int h[256 * G];
    __shared__ int soffs[G];
    const int tid = threadIdx.x;
    for (int e = tid; e < NB * G; e += 256) h[e] = hist[e];
    __syncthreads();
    if (tid < G) {
        int run = 0;
        for (int b = 0; b < NB; ++b) {
            const int v = h[b * G + tid];
            h[b * G + tid] = run;
            run += v;
        }
        counts[tid] = run;
    }
    __syncthreads();
    if (tid == 0) {
        int o = 0;
        for (int gv = 0; gv < G; ++gv) { soffs[gv] = o; offs[gv] = o; o += counts[gv]; }
    }
    __syncthreads();
    for (int e = tid; e < NB * G; e += 256) hist[e] = h[e] + soffs[e & (G - 1)];
}

// ---- pass 3: deterministic rank-based scatter (ballot rank, no atomics) ----
__global__ __launch_bounds__(256) void k_scatter2(
    const int* __restrict__ target, const int* __restrict__ batch,
    const int* __restrict__ base, int* __restrict__ idxbuf, int n) {
    __shared__ int wbase[4][G];
    __shared__ unsigned short wcnt[4][G];
    const int tid = threadIdx.x;
    const int i = blockIdx.x * 256 + tid;
    const int wave = tid >> 6, lane = tid & 63;
    const bool valid = i < n;
    const int g = valid ? group_of(target[i], batch[i]) : -1;
    int rank = 0;
    #pragma unroll
    for (int gv = 0; gv < G; ++gv) {
        unsigned long long m = __ballot(g == gv);
        if (g == gv) rank = __popcll(m & ((1ull << lane) - 1ull));
        if (lane == 0) wcnt[wave][gv] = (unsigned short)__popcll(m);
    }
    __syncthreads();
    if (tid < G) {
        int run = base[blockIdx.x * G + tid];
        #pragma unroll
        for (int w = 0; w < 4; ++w) { wbase[w][tid] = run; run += wcnt[w][tid]; }
    }
    __syncthreads();
    if (valid) idxbuf[wbase[wave][g] + rank] = i;
}

// grouped split-K SYRK: partial[slot][g] += Z_chunk^T Z_chunk (128x128 tiles)
__global__ __launch_bounds__(256) void k_gram(
    const float* __restrict__ feat, const float* __restrict__ rnorm,
    const int* __restrict__ idxbuf, const int* __restrict__ counts,
    const int* __restrict__ offs, float* __restrict__ part) {
    const int p  = blockIdx.x;
    const int g  = blockIdx.y;
    const int slot = blockIdx.z;
    const int CH = gridDim.z;
    const int ti = (p >= 1) ? 1 : 0, tj = (p == 2) ? 1 : 0;
    const int n = counts[g], off = offs[g];

    __shared__ float LA[32][132];
    __shared__ float LB[32][132];

    const int tid = threadIdx.x;
    const int ty = tid >> 4, tx = tid & 15;
    const int rr = tid >> 3, seg = tid & 7;

    float acc[8][8];
    #pragma unroll
    for (int i = 0; i < 8; ++i)
        #pragma unroll
        for (int j = 0; j < 8; ++j) acc[i][j] = 0.0f;

    for (int c = slot; c * CS < n; c += CH) {
        const int cbase = c * CS;
        const int cend  = (cbase + CS < n) ? cbase + CS : n;
        for (int sub = cbase; sub < cend; sub += 32) {
            const int r = sub + rr;
            const bool valid = (r < cend);
            const int row = valid ? idxbuf[off + r] : 0;
            const float inv = valid ? rnorm[row] : 0.0f;
            const float* bA = feat + (size_t)row * D + ti * 128 + seg * 16;
            float4 va[4], vb[4];
            #pragma unroll
            for (int q = 0; q < 4; ++q) {
                float4 v = *(const float4*)(bA + q * 4);
                v.x *= inv; v.y *= inv; v.z *= inv; v.w *= inv;
                va[q] = v;
            }
            if (p == 1) {
                const float* bB = feat + (size_t)row * D + seg * 16;
                #pragma unroll
                for (int q = 0; q < 4; ++q) {
                    float4 v = *(const float4*)(bB + q * 4);
                    v.x *= inv; v.y *= inv; v.z *= inv; v.w *= inv;
                    vb[q] = v;
                }
            }
            __syncthreads();
            #pragma unroll
            for (int q = 0; q < 4; ++q)
                *(float4*)&LA[rr][seg * 16 + q * 4] = va[q];
            if (p == 1) {
                #pragma unroll
                for (int q = 0; q < 4; ++q)
                    *(float4*)&LB[rr][seg * 16 + q * 4] = vb[q];
            }
            __syncthreads();

            const float (*Bt)[132] = (p == 1) ? LB : LA;
            #pragma unroll 4
            for (int r2 = 0; r2 < 32; ++r2) {
                const float* Ar = &LA[r2][0];
                const float* Br = &Bt[r2][0];
                float4 a0 = *(const float4*)(Ar + ty * 8);
                float4 a1 = *(const float4*)(Ar + ty * 8 + 4);
                float4 b0 = *(const float4*)(Br + tx * 4);
                float4 b1 = *(const float4*)(Br + 64 + tx * 4);
                float av[8] = {a0.x,a0.y,a0.z,a0.w,a1.x,a1.y,a1.z,a1.w};
                float bv[8] = {b0.x,b0.y,b0.z,b0.w,b1.x,b1.y,b1.z,b1.w};
                #pragma unroll
                for (int i = 0; i < 8; ++i)
                    #pragma unroll
                    for (int j = 0; j < 8; ++j)
                        acc[i][j] = fmaf(av[i], bv[j], acc[i][j]);
            }
        }
    }

    float* base = part + ((size_t)slot * G + g) * (D * D);
    #pragma unroll
    for (int i = 0; i < 8; ++i) {
        const int row_g = ti * 128 + ty * 8 + i;
        float4 lo = {acc[i][0], acc[i][1], acc[i][2], acc[i][3]};
        float4 hi = {acc[i][4], acc[i][5], acc[i][6], acc[i][7]};
        *(float4*)(base + (size_t)row_g * D + tj * 128 + tx * 4)      = lo;
        *(float4*)(base + (size_t)row_g * D + tj * 128 + 64 + tx * 4) = hi;
    }
    if (p == 1) {
        #pragma unroll
        for (int j = 0; j < 8; ++j) {
            const int col_g = (j < 4) ? (tx * 4 + j) : (64 + tx * 4 + (j - 4));
            float4 lo = {acc[0][j], acc[1][j], acc[2][j], acc[3][j]};
            float4 hi = {acc[4][j], acc[5][j], acc[6][j], acc[7][j]};
            float* dst = base + (size_t)col_g * D + 128 + ty * 8;
            *(float4*)dst       = lo;
            *(float4*)(dst + 4) = hi;
        }
    }
}

__global__ void k_reduce(const float* __restrict__ part, float* __restrict__ gram, int CH) {
    const int total4 = G * D * D / 4;
    const float4* p4 = (const float4*)part;
    float4* g4 = (float4*)gram;
    for (int e = blockIdx.x * blockDim.x + threadIdx.x; e < total4; e += gridDim.x * blockDim.x) {
        float4 s = p4[e];
        for (int ch = 1; ch < CH; ++ch) {
            float4 t = p4[(size_t)ch * total4 + e];
            s.x += t.x; s.y += t.y; s.z += t.z; s.w += t.w;
        }
        g4[e] = s;
    }
}

// packed-lower-triangle row offset, rows padded to 4 floats
__device__ __forceinline__ int rowoff(int i) {
    int q = i >> 2, s = i & 3;
    return 4 * (2 * q * (q + 1) + s * (q + 1));
}

// one block per group: blocked (BK=16) in-LDS Cholesky, logdet = sum log(pivots)
__global__ __launch_bounds__(512) void k_chol(
    const float* __restrict__ gram, const int* __restrict__ counts,
    float* __restrict__ logdetbuf) {
    const int g = blockIdx.x;
    const int tid = threadIdx.x;
    __shared__ float T[33280];        // 130 KB packed lower triangle
    __shared__ float PT[16 * 256];    // 16 KB transposed panel
    __shared__ float L11b[16][16];
    __shared__ float invdb[16];

    const int n = counts[g];
    const float nn = fmaxf((float)n, 1.0f);
    const float aa = (float)D / (nn * 0.04f);   // D / (n * eps^2)
    const float dg = 1.0f + 1e-6f;

    // ---- load M = a*gram + (1+1e-6)I into packed triangle (2 threads/row) ----
    {
        const int r = tid >> 1, half = tid & 1;
        const int nch = (r >> 2) + 1;
        const int mid = (nch + 1) >> 1;
        const int clo = half ? mid : 0;
        const int chi = half ? nch : mid;
        const float* Gr = gram + (size_t)g * (D * D) + (size_t)r * D;
        float* Tr = T + rowoff(r);
        for (int c = clo; c < chi; ++c) {
            float4 v = *(const float4*)(Gr + c * 4);
            v.x *= aa; v.y *= aa; v.z *= aa; v.w *= aa;
            v.x += (c * 4 + 0 == r) ? dg : 0.0f;
            v.y += (c * 4 + 1 == r) ? dg : 0.0f;
            v.z += (c * 4 + 2 == r) ? dg : 0.0f;
            v.w += (c * 4 + 3 == r) ? dg : 0.0f;
            *(float4*)(Tr + c * 4) = v;
        }
    }
    __syncthreads();

    float ldacc = 0.0f;

    for (int kb = 0; kb < 16; ++kb) {
        const int kb16 = kb * 16;

        // ---- A: diagonal block factor (lanes 0-15, register rows) ----
        if (tid < 16) {
            const int lane = tid;
            const int r = kb16 + lane;
            float rr[16];
            const float* Tr = T + rowoff(r);
            #pragma unroll
            for (int q = 0; q < 4; ++q) {
                if (kb16 + q * 4 <= r) {
                    float4 v = *(const float4*)(Tr + kb16 + q * 4);
                    rr[q*4+0] = v.x; rr[q*4+1] = v.y; rr[q*4+2] = v.z; rr[q*4+3] = v.w;
                } else {
                    rr[q*4+0] = 0.0f; rr[q*4+1] = 0.0f; rr[q*4+2] = 0.0f; rr[q*4+3] = 0.0f;
                }
            }
            #pragma unroll
            for (int pc = 0; pc < 16; ++pc) {
                const float piv = __shfl(rr[pc], pc);
                ldacc += logf(piv);
                const float inv = 1.0f / sqrtf(piv);
                if (lane == 0) invdb[pc] = inv;
                if (lane > pc) rr[pc] *= inv;
                #pragma unroll
                for (int j = pc + 1; j < 16; ++j) {
                    const float Lj = __shfl(rr[pc], j);
                    if (lane >= j) rr[j] -= rr[pc] * Lj;
                }
            }
            #pragma unroll
            for (int pp = 0; pp < 16; ++pp)
                if (pp < lane) L11b[lane][pp] = rr[pp];
        }
        __syncthreads();

        const int pstart = kb16 + 16;
        const int R = 256 - pstart;

        // ---- B: TRSM, one row per thread; write panel transposed ----
        if (tid < R) {
            const int r = pstart + tid;
            const float* Tr = T + rowoff(r) + kb16;
            float x[16];
            {
                float4 v0 = *(const float4*)(Tr + 0);
                float4 v1 = *(const float4*)(Tr + 4);
                float4 v2 = *(const float4*)(Tr + 8);
                float4 v3 = *(const float4*)(Tr + 12);
                x[0]=v0.x; x[1]=v0.y; x[2]=v0.z; x[3]=v0.w;
                x[4]=v1.x; x[5]=v1.y; x[6]=v1.z; x[7]=v1.w;
                x[8]=v2.x; x[9]=v2.y; x[10]=v2.z; x[11]=v2.w;
                x[12]=v3.x; x[13]=v3.y; x[14]=v3.z; x[15]=v3.w;
            }
            #pragma unroll
            for (int c = 0; c < 16; ++c) {
                float Lr[16];
                {
                    float4 L0 = *(const float4*)&L11b[c][0];
                    float4 L1 = *(const float4*)&L11b[c][4];
                    float4 L2 = *(const float4*)&L11b[c][8];
                    float4 L3 = *(const float4*)&L11b[c][12];
                    Lr[0]=L0.x; Lr[1]=L0.y; Lr[2]=L0.z; Lr[3]=L0.w;
                    Lr[4]=L1.x; Lr[5]=L1.y; Lr[6]=L1.z; Lr[7]=L1.w;
                    Lr[8]=L2.x; Lr[9]=L2.y; Lr[10]=L2.z; Lr[11]=L2.w;
                    Lr[12]=L3.x; Lr[13]=L3.y; Lr[14]=L3.z; Lr[15]=L3.w;
                }
                float s = x[c];
                #pragma unroll
                for (int pp = 0; pp < 16; ++pp)
                    if (pp < c) s -= x[pp] * Lr[pp];
                x[c] = s * invdb[c];
            }
            #pragma unroll
            for (int pp = 0; pp < 16; ++pp)
                PT[pp * 256 + r] = x[pp];
        }
        __syncthreads();

        // ---- C: trailing SYRK update, 32x32 macro per wave, 4x4 per lane ----
        if (R > 0) {
            const int MRm = (R + 31) >> 5;
            const int nmac = MRm * (MRm + 1) / 2;
            const int wave = tid >> 6;
            const int lane = tid & 63;
            const int li = lane >> 3, lj = lane & 7;
            for (int idx = wave; idx < nmac; idx += 8) {
                int MI = 0, base = 0;
                while (base + MI + 1 <= idx) { base += MI + 1; MI++; }
                const int MJ = idx - base;
                const int r0 = pstart + MI * 32 + li * 4;
                const int c0 = pstart + MJ * 32 + lj * 4;
                if (r0 >= 256 || c0 >= 256) continue;
                if (c0 > r0 + 3) continue;

                float acc[4][4];
                #pragma unroll
                for (int qi = 0; qi < 4; ++qi)
                    #pragma unroll
                    for (int qj = 0; qj < 4; ++qj) acc[qi][qj] = 0.0f;

                #pragma unroll
                for (int pp = 0; pp < 16; ++pp) {
                    const float4 av = *(const float4*)&PT[pp * 256 + r0];
                    const float4 bv = *(const float4*)&PT[pp * 256 + c0];
                    float a4[4] = {av.x, av.y, av.z, av.w};
                    float b4[4] = {bv.x, bv.y, bv.z, bv.w};
                    #pragma unroll
                    for (int qi = 0; qi < 4; ++qi)
                        #pragma unroll
                        for (int qj = 0; qj < 4; ++qj)
                            acc[qi][qj] = fmaf(a4[qi], b4[qj], acc[qi][qj]);
                }

                #pragma unroll
                for (int qi = 0; qi < 4; ++qi) {
                    const int r = r0 + qi;
                    float* cp = T + rowoff(r) + c0;
                    if (c0 + 3 <= r) {
                        float4 t = *(float4*)cp;
                        t.x -= acc[qi][0]; t.y -= acc[qi][1];
                        t.z -= acc[qi][2]; t.w -= acc[qi][3];
                        *(float4*)cp = t;
                    } else {
                        #pragma unroll
                        for (int qj = 0; qj < 4; ++qj)
                            if (c0 + qj <= r) cp[qj] -= acc[qi][qj];
                    }
                }
            }
        }
        __syncthreads();
    }

    if (tid == 0) logdetbuf[g] = ldacc;
}

__global__ void k_final(const float* __restrict__ ld, const int* __restrict__ counts,
                        float* __restrict__ out) {
    if (threadIdx.x == 0 && blockIdx.x == 0) {
        const float min_tcr = 0.5f * logf(256.0f);
        const float log_diag = logf(1.0f + 1e-6f + 1e-12f);
        float s[2] = {0.0f, 0.0f}, c2[2] = {0.0f, 0.0f};
        for (int g = 0; g < G; ++g) {
            const float n = (float)counts[g];
            const float nn = fmaxf(n, 1.0f);
            const float logdet = ld[g] + (nn - (float)D) * log_diag;
            const float tcr = 0.5f * logdet;
            const float def = fmaxf(min_tcr - tcr, 0.0f);
            if (counts[g] >= MINS) { s[g / NC] += def; c2[g / NC] += 1.0f; }
        }
        float avg = 0.0f;
        for (int b = 0; b < 2; ++b)
            avg += (c2[b] > 0.0f) ? s[b] / fmaxf(c2[b], 1.0f) : 0.0f;
        avg *= 0.5f;
        out[0] = 1.0f * 0.05f * avg;
    }
}

extern "C" void kernel_launch(void* const* d_in, const int* in_sizes, int n_in,
                              void* d_out, int out_size, void* d_ws, size_t ws_size,
                              hipStream_t stream) {
    const int*   target = (const int*)d_in[1];
    const float* feat   = (const float*)d_in[2];
    const int*   batch  = (const int*)d_in[3];
    float* out = (float*)d_out;
    char* ws = (char*)d_ws;
    const int n = in_sizes[1];

    int*   counts = (int*)(ws + OFF_CNT);
    int*   offs   = (int*)(ws + OFF_OFFS);
    float* logdet = (float*)(ws + OFF_LOGDET);
    int*   hist   = (int*)(ws + OFF_HIST);
    int*   idxbuf = (int*)(ws + OFF_IDX);
    float* rnorm  = (float*)(ws + OFF_RNORM);
    float* gram   = (float*)(ws + OFF_GRAM);

    long avail = (long)ws_size - (long)OFF_PART;
    int CH;
    float* part;
    bool need_reduce;
    if (avail >= (long)GRAM_BYTES) {
        long c = avail / (long)GRAM_BYTES;
        CH = (int)(c < 8 ? c : 8);
        part = (float*)(ws + OFF_PART);
        need_reduce = true;
    } else {
        CH = 1;
        part = gram;
        need_reduce = false;
    }

    const int NB = (n + 255) / 256;   // 256 for n=65536 (k_prefix2 LDS sized for <=256)

    k_norm    <<<(n + 3) / 4, 256, 0, stream>>>(feat, rnorm, n);
    k_hist    <<<NB, 256, 0, stream>>>(target, batch, hist, n);
    k_prefix2 <<<1, 256, 0, stream>>>(hist, counts, offs, NB);
    k_scatter2<<<NB, 256, 0, stream>>>(target, batch, hist, idxbuf, n);
    k_gram    <<<dim3(3, G, CH), 256, 0, stream>>>(feat, rnorm, idxbuf, counts, offs, part);
    if (need_reduce)
        k_reduce<<<256, 256, 0, stream>>>(part, gram, CH);
    k_chol    <<<G, 512, 0, stream>>>(gram, counts, logdet);
    k_final   <<<1, 64, 0, stream>>>(logdet, counts, out);
}

// Round 4
// 291.181 us; speedup vs baseline: 3.9005x; 1.0172x over previous
//
#include <hip/hip_runtime.h>
#include <math.h>

#define D 256
#define NC 8
#define G 16
#define MINS 10
#define CS 512

// ---- workspace layout (bytes) ----
#define OFF_CNT     0u
#define OFF_OFFS    128u
#define OFF_LOGDET  256u
#define OFF_HIST    1024u                           // NB*16 ints (NB<=256 -> 16KB)
#define OFF_IDX     20480u
#define OFF_RNORM   (OFF_IDX + 65536u*4u)           // 282,624
#define OFF_GRAM    (1u<<20)                         // 1 MB
#define GRAM_BYTES  (G*D*D*4u)                       // 4 MB
#define OFF_PART    (OFF_GRAM + GRAM_BYTES)          // 5 MB

__global__ void k_norm(const float* __restrict__ feat, float* __restrict__ rnorm, int n) {
    int row = blockIdx.x * 4 + (threadIdx.x >> 6);
    if (row >= n) return;
    int lane = threadIdx.x & 63;
    const float4 v = *(const float4*)(feat + (size_t)row * D + lane * 4);
    float s = v.x*v.x + v.y*v.y + v.z*v.z + v.w*v.w;
    #pragma unroll
    for (int d = 32; d; d >>= 1) s += __shfl_xor(s, d, 64);
    if (lane == 0) rnorm[row] = 1.0f / fmaxf(sqrtf(s), 1e-12f);
}

__device__ __forceinline__ int group_of(int t, int b) {
    t = t < 0 ? 0 : (t > NC - 1 ? NC - 1 : t);
    return b * NC + t;
}

// ---- pass 1: per-block 16-bin histogram via ballots (no atomics) ----
__global__ __launch_bounds__(256) void k_hist(
    const int* __restrict__ target, const int* __restrict__ batch,
    int* __restrict__ hist, int n) {
    __shared__ unsigned short wcnt[4][G];
    const int tid = threadIdx.x;
    const int i = blockIdx.x * 256 + tid;
    const int wave = tid >> 6, lane = tid & 63;
    const bool valid = i < n;
    const int g = valid ? group_of(target[i], batch[i]) : -1;
    #pragma unroll
    for (int gv = 0; gv < G; ++gv) {
        unsigned long long m = __ballot(g == gv);
        if (lane == 0) wcnt[wave][gv] = (unsigned short)__popcll(m);
    }
    __syncthreads();
    if (tid < G)
        hist[blockIdx.x * G + tid] =
            (int)wcnt[0][tid] + wcnt[1][tid] + wcnt[2][tid] + wcnt[3][tid];
}

// ---- pass 2: exclusive prefix over blocks per group + group offsets ----
__global__ __launch_bounds__(256) void k_prefix2(
    int* __restrict__ hist, int* __restrict__ counts, int* __restrict__ offs, int NB) {
    __shared__ int h[256 * G];
    __shared__ int soffs[G];
    const int tid = threadIdx.x;
    for (int e = tid; e < NB * G; e += 256) h[e] = hist[e];
    __syncthreads();
    if (tid < G) {
        int run = 0;
        for (int b = 0; b < NB; ++b) {
            const int v = h[b * G + tid];
            h[b * G + tid] = run;
            run += v;
        }
        counts[tid] = run;
    }
    __syncthreads();
    if (tid == 0) {
        int o = 0;
        for (int gv = 0; gv < G; ++gv) { soffs[gv] = o; offs[gv] = o; o += counts[gv]; }
    }
    __syncthreads();
    for (int e = tid; e < NB * G; e += 256) hist[e] = h[e] + soffs[e & (G - 1)];
}

// ---- pass 3: deterministic rank-based scatter (ballot rank, no atomics) ----
__global__ __launch_bounds__(256) void k_scatter2(
    const int* __restrict__ target, const int* __restrict__ batch,
    const int* __restrict__ base, int* __restrict__ idxbuf, int n) {
    __shared__ int wbase[4][G];
    __shared__ unsigned short wcnt[4][G];
    const int tid = threadIdx.x;
    const int i = blockIdx.x * 256 + tid;
    const int wave = tid >> 6, lane = tid & 63;
    const bool valid = i < n;
    const int g = valid ? group_of(target[i], batch[i]) : -1;
    int rank = 0;
    #pragma unroll
    for (int gv = 0; gv < G; ++gv) {
        unsigned long long m = __ballot(g == gv);
        if (g == gv) rank = __popcll(m & ((1ull << lane) - 1ull));
        if (lane == 0) wcnt[wave][gv] = (unsigned short)__popcll(m);
    }
    __syncthreads();
    if (tid < G) {
        int run = base[blockIdx.x * G + tid];
        #pragma unroll
        for (int w = 0; w < 4; ++w) { wbase[w][tid] = run; run += wcnt[w][tid]; }
    }
    __syncthreads();
    if (valid) idxbuf[wbase[wave][g] + rank] = i;
}

// grouped split-K SYRK: partial[slot][g] += Z_chunk^T Z_chunk (128x128 tiles)
__global__ __launch_bounds__(256) void k_gram(
    const float* __restrict__ feat, const float* __restrict__ rnorm,
    const int* __restrict__ idxbuf, const int* __restrict__ counts,
    const int* __restrict__ offs, float* __restrict__ part) {
    const int p  = blockIdx.x;
    const int g  = blockIdx.y;
    const int slot = blockIdx.z;
    const int CH = gridDim.z;
    const int ti = (p >= 1) ? 1 : 0, tj = (p == 2) ? 1 : 0;
    const int n = counts[g], off = offs[g];

    __shared__ float LA[32][132];
    __shared__ float LB[32][132];

    const int tid = threadIdx.x;
    const int ty = tid >> 4, tx = tid & 15;
    const int rr = tid >> 3, seg = tid & 7;

    float acc[8][8];
    #pragma unroll
    for (int i = 0; i < 8; ++i)
        #pragma unroll
        for (int j = 0; j < 8; ++j) acc[i][j] = 0.0f;

    for (int c = slot; c * CS < n; c += CH) {
        const int cbase = c * CS;
        const int cend  = (cbase + CS < n) ? cbase + CS : n;
        for (int sub = cbase; sub < cend; sub += 32) {
            const int r = sub + rr;
            const bool valid = (r < cend);
            const int row = valid ? idxbuf[off + r] : 0;
            const float inv = valid ? rnorm[row] : 0.0f;
            const float* bA = feat + (size_t)row * D + ti * 128 + seg * 16;
            float4 va[4], vb[4];
            #pragma unroll
            for (int q = 0; q < 4; ++q) {
                float4 v = *(const float4*)(bA + q * 4);
                v.x *= inv; v.y *= inv; v.z *= inv; v.w *= inv;
                va[q] = v;
            }
            if (p == 1) {
                const float* bB = feat + (size_t)row * D + seg * 16;
                #pragma unroll
                for (int q = 0; q < 4; ++q) {
                    float4 v = *(const float4*)(bB + q * 4);
                    v.x *= inv; v.y *= inv; v.z *= inv; v.w *= inv;
                    vb[q] = v;
                }
            }
            __syncthreads();
            #pragma unroll
            for (int q = 0; q < 4; ++q)
                *(float4*)&LA[rr][seg * 16 + q * 4] = va[q];
            if (p == 1) {
                #pragma unroll
                for (int q = 0; q < 4; ++q)
                    *(float4*)&LB[rr][seg * 16 + q * 4] = vb[q];
            }
            __syncthreads();

            const float (*Bt)[132] = (p == 1) ? LB : LA;
            #pragma unroll 4
            for (int r2 = 0; r2 < 32; ++r2) {
                const float* Ar = &LA[r2][0];
                const float* Br = &Bt[r2][0];
                float4 a0 = *(const float4*)(Ar + ty * 8);
                float4 a1 = *(const float4*)(Ar + ty * 8 + 4);
                float4 b0 = *(const float4*)(Br + tx * 4);
                float4 b1 = *(const float4*)(Br + 64 + tx * 4);
                float av[8] = {a0.x,a0.y,a0.z,a0.w,a1.x,a1.y,a1.z,a1.w};
                float bv[8] = {b0.x,b0.y,b0.z,b0.w,b1.x,b1.y,b1.z,b1.w};
                #pragma unroll
                for (int i = 0; i < 8; ++i)
                    #pragma unroll
                    for (int j = 0; j < 8; ++j)
                        acc[i][j] = fmaf(av[i], bv[j], acc[i][j]);
            }
        }
    }

    float* base = part + ((size_t)slot * G + g) * (D * D);
    #pragma unroll
    for (int i = 0; i < 8; ++i) {
        const int row_g = ti * 128 + ty * 8 + i;
        float4 lo = {acc[i][0], acc[i][1], acc[i][2], acc[i][3]};
        float4 hi = {acc[i][4], acc[i][5], acc[i][6], acc[i][7]};
        *(float4*)(base + (size_t)row_g * D + tj * 128 + tx * 4)      = lo;
        *(float4*)(base + (size_t)row_g * D + tj * 128 + 64 + tx * 4) = hi;
    }
    if (p == 1) {
        #pragma unroll
        for (int j = 0; j < 8; ++j) {
            const int col_g = (j < 4) ? (tx * 4 + j) : (64 + tx * 4 + (j - 4));
            float4 lo = {acc[0][j], acc[1][j], acc[2][j], acc[3][j]};
            float4 hi = {acc[4][j], acc[5][j], acc[6][j], acc[7][j]};
            float* dst = base + (size_t)col_g * D + 128 + ty * 8;
            *(float4*)dst       = lo;
            *(float4*)(dst + 4) = hi;
        }
    }
}

__global__ void k_reduce(const float* __restrict__ part, float* __restrict__ gram, int CH) {
    const int total4 = G * D * D / 4;
    const float4* p4 = (const float4*)part;
    float4* g4 = (float4*)gram;
    for (int e = blockIdx.x * blockDim.x + threadIdx.x; e < total4; e += gridDim.x * blockDim.x) {
        float4 s = p4[e];
        for (int ch = 1; ch < CH; ++ch) {
            float4 t = p4[(size_t)ch * total4 + e];
            s.x += t.x; s.y += t.y; s.z += t.z; s.w += t.w;
        }
        g4[e] = s;
    }
}

// packed-lower-triangle row offset, rows padded to 4 floats
__device__ __forceinline__ int rowoff(int i) {
    int q = i >> 2, s = i & 3;
    return 4 * (2 * q * (q + 1) + s * (q + 1));
}

// 16x16 diag-block factor on lanes 0-15 (register rows, shfl broadcasts).
// Writes L11c column-major (L11c[c][j] = L[j][c]) and invdb; pivot log is
// latched per-lane (one __logf per panel per lane, OFF the pivot chain).
__device__ __forceinline__ void factor_diag(
    float* T, float (*L11c)[16], float* invdb, int kb16, int lane, float& plog) {
    const int r = kb16 + lane;
    float rr[16];
    const float* Tr = T + rowoff(r);
    #pragma unroll
    for (int q = 0; q < 4; ++q) {
        if (kb16 + q * 4 <= r) {
            float4 v = *(const float4*)(Tr + kb16 + q * 4);
            rr[q*4+0] = v.x; rr[q*4+1] = v.y; rr[q*4+2] = v.z; rr[q*4+3] = v.w;
        } else {
            rr[q*4+0] = 0.0f; rr[q*4+1] = 0.0f; rr[q*4+2] = 0.0f; rr[q*4+3] = 0.0f;
        }
    }
    float mypiv = 1.0f, myinv = 1.0f;
    #pragma unroll
    for (int pc = 0; pc < 16; ++pc) {
        const float piv = __shfl(rr[pc], pc);
        const float inv = 1.0f / sqrtf(piv);
        mypiv = (lane == pc) ? piv : mypiv;
        myinv = (lane == pc) ? inv : myinv;
        if (lane > pc) rr[pc] *= inv;
        #pragma unroll
        for (int j = pc + 1; j < 16; ++j) {
            const float Lj = __shfl(rr[pc], j);
            if (lane >= j) rr[j] = fmaf(-rr[pc], Lj, rr[j]);
        }
    }
    plog += __logf(mypiv);
    invdb[lane] = myinv;
    #pragma unroll
    for (int pp = 0; pp < 16; ++pp)
        if (pp < lane) L11c[pp][lane] = rr[pp];
}

// one block per group: blocked (BK=16) in-LDS Cholesky.
// Panel k+1's diag factor is hidden inside panel k's trailing update (wave 0
// owns tile(0,0) which covers the next diag block, then factors it while
// waves 1-7 drain the remaining tiles from an LDS work pool).
__global__ __launch_bounds__(512) void k_chol(
    const float* __restrict__ gram, const int* __restrict__ counts,
    float* __restrict__ logdetbuf) {
    const int g = blockIdx.x;
    const int tid = threadIdx.x;
    __shared__ float T[33280];        // 130 KB packed lower triangle
    __shared__ float PT[16 * 256];    // 16 KB transposed panel
    __shared__ float L11c[2][16][16]; // column-major diag factor, double-buffered
    __shared__ float invdb[2][16];
    __shared__ int tctr;

    const int n = counts[g];
    const float nn = fmaxf((float)n, 1.0f);
    const float aa = (float)D / (nn * 0.04f);   // D / (n * eps^2)
    const float dg = 1.0f + 1e-6f;

    // ---- load M = a*gram + (1+1e-6)I into packed triangle (2 threads/row) ----
    {
        const int r = tid >> 1, half = tid & 1;
        const int nch = (r >> 2) + 1;
        const int mid = (nch + 1) >> 1;
        const int clo = half ? mid : 0;
        const int chi = half ? nch : mid;
        const float* Gr = gram + (size_t)g * (D * D) + (size_t)r * D;
        float* Tr = T + rowoff(r);
        for (int c = clo; c < chi; ++c) {
            float4 v = *(const float4*)(Gr + c * 4);
            v.x *= aa; v.y *= aa; v.z *= aa; v.w *= aa;
            v.x += (c * 4 + 0 == r) ? dg : 0.0f;
            v.y += (c * 4 + 1 == r) ? dg : 0.0f;
            v.z += (c * 4 + 2 == r) ? dg : 0.0f;
            v.w += (c * 4 + 3 == r) ? dg : 0.0f;
            *(float4*)(Tr + c * 4) = v;
        }
    }
    __syncthreads();

    float plog = 0.0f;
    const int wave = tid >> 6;
    const int lane = tid & 63;
    const int li = lane >> 3, lj = lane & 7;

    if (tid < 16) factor_diag(T, L11c[0], invdb[0], 0, tid, plog);
    __syncthreads();

    for (int kb = 0; kb < 15; ++kb) {
        const int kb16 = kb * 16;
        const int par = kb & 1;
        const int pstart = kb16 + 16;
        const int R = 256 - pstart;

        // ---- B: right-looking TRSM, one row/thread, pipelined column loads ----
        if (tid < R) {
            const int r = pstart + tid;
            const float* Tr = T + rowoff(r) + kb16;
            float x[16];
            {
                float4 v0 = *(const float4*)(Tr + 0);
                float4 v1 = *(const float4*)(Tr + 4);
                float4 v2 = *(const float4*)(Tr + 8);
                float4 v3 = *(const float4*)(Tr + 12);
                x[0]=v0.x; x[1]=v0.y; x[2]=v0.z; x[3]=v0.w;
                x[4]=v1.x; x[5]=v1.y; x[6]=v1.z; x[7]=v1.w;
                x[8]=v2.x; x[9]=v2.y; x[10]=v2.z; x[11]=v2.w;
                x[12]=v3.x; x[13]=v3.y; x[14]=v3.z; x[15]=v3.w;
            }
            float iv[16];
            {
                const float* ivp = invdb[par];
                float4 i0 = *(const float4*)(ivp + 0);
                float4 i1 = *(const float4*)(ivp + 4);
                float4 i2 = *(const float4*)(ivp + 8);
                float4 i3 = *(const float4*)(ivp + 12);
                iv[0]=i0.x; iv[1]=i0.y; iv[2]=i0.z; iv[3]=i0.w;
                iv[4]=i1.x; iv[5]=i1.y; iv[6]=i1.z; iv[7]=i1.w;
                iv[8]=i2.x; iv[9]=i2.y; iv[10]=i2.z; iv[11]=i2.w;
                iv[12]=i3.x; iv[13]=i3.y; iv[14]=i3.z; iv[15]=i3.w;
            }
            const float (*Lc)[16] = L11c[par];
            float4 n0 = *(const float4*)&Lc[0][0];
            float4 n1 = *(const float4*)&Lc[0][4];
            float4 n2 = *(const float4*)&Lc[0][8];
            float4 n3 = *(const float4*)&Lc[0][12];
            #pragma unroll
            for (int c = 0; c < 16; ++c) {
                const float col[16] = {n0.x,n0.y,n0.z,n0.w, n1.x,n1.y,n1.z,n1.w,
                                       n2.x,n2.y,n2.z,n2.w, n3.x,n3.y,n3.z,n3.w};
                if (c < 15) {
                    n0 = *(const float4*)&Lc[c+1][0];
                    n1 = *(const float4*)&Lc[c+1][4];
                    n2 = *(const float4*)&Lc[c+1][8];
                    n3 = *(const float4*)&Lc[c+1][12];
                }
                const float xc = x[c] * iv[c];
                x[c] = xc;
                #pragma unroll
                for (int j = 0; j < 16; ++j)
                    if (j > c) x[j] = fmaf(-xc, col[j], x[j]);
            }
            #pragma unroll
            for (int pp = 0; pp < 16; ++pp)
                PT[pp * 256 + r] = x[pp];
        }
        if (tid == 0) tctr = 1;
        __syncthreads();

        // ---- C: trailing SYRK (dynamic tile pool) + hidden factor of panel k+1 ----
        const int MRm = (R + 31) >> 5;
        const int nmac = MRm * (MRm + 1) / 2;

        auto do_tile = [&](int idx) {
            int MI = 0, base = 0;
            while (base + MI + 1 <= idx) { base += MI + 1; ++MI; }
            const int MJ = idx - base;
            const int r0 = pstart + MI * 32 + li * 4;
            const int c0 = pstart + MJ * 32 + lj * 4;
            if (r0 >= 256 || c0 >= 256) return;
            if (c0 > r0 + 3) return;
            float acc[4][4];
            #pragma unroll
            for (int qi = 0; qi < 4; ++qi)
                #pragma unroll
                for (int qj = 0; qj < 4; ++qj) acc[qi][qj] = 0.0f;
            #pragma unroll
            for (int pq = 0; pq < 4; ++pq) {
                float4 a[4], b[4];
                #pragma unroll
                for (int q = 0; q < 4; ++q) {
                    a[q] = *(const float4*)&PT[(pq * 4 + q) * 256 + r0];
                    b[q] = *(const float4*)&PT[(pq * 4 + q) * 256 + c0];
                }
                #pragma unroll
                for (int q = 0; q < 4; ++q) {
                    float a4[4] = {a[q].x, a[q].y, a[q].z, a[q].w};
                    float b4[4] = {b[q].x, b[q].y, b[q].z, b[q].w};
                    #pragma unroll
                    for (int qi = 0; qi < 4; ++qi)
                        #pragma unroll
                        for (int qj = 0; qj < 4; ++qj)
                            acc[qi][qj] = fmaf(a4[qi], b4[qj], acc[qi][qj]);
                }
            }
            #pragma unroll
            for (int qi = 0; qi < 4; ++qi) {
                const int r = r0 + qi;
                float* cp = T + rowoff(r) + c0;
                if (c0 + 3 <= r) {
                    float4 t = *(float4*)cp;
                    t.x -= acc[qi][0]; t.y -= acc[qi][1];
                    t.z -= acc[qi][2]; t.w -= acc[qi][3];
                    *(float4*)cp = t;
                } else {
                    #pragma unroll
                    for (int qj = 0; qj < 4; ++qj)
                        if (c0 + qj <= r) cp[qj] -= acc[qi][qj];
                }
            }
        };

        if (wave == 0) {
            do_tile(0);   // covers rows/cols [pstart, pstart+31]: next diag block
            if (lane < 16)
                factor_diag(T, L11c[par ^ 1], invdb[par ^ 1], pstart, lane, plog);
        }
        int grab;
        if (lane == 0) grab = atomicAdd(&tctr, 1);
        grab = __shfl(grab, 0);
        while (grab < nmac) {
            do_tile(grab);
            if (lane == 0) grab = atomicAdd(&tctr, 1);
            grab = __shfl(grab, 0);
        }
        __syncthreads();
    }

    if (tid < 16) {
        #pragma unroll
        for (int d = 8; d; d >>= 1) plog += __shfl_xor(plog, d);
        if (tid == 0) logdetbuf[g] = plog;
    }
}

__global__ void k_final(const float* __restrict__ ld, const int* __restrict__ counts,
                        float* __restrict__ out) {
    if (threadIdx.x == 0 && blockIdx.x == 0) {
        const float min_tcr = 0.5f * logf(256.0f);
        const float log_diag = logf(1.0f + 1e-6f + 1e-12f);
        float s[2] = {0.0f, 0.0f}, c2[2] = {0.0f, 0.0f};
        for (int g = 0; g < G; ++g) {
            const float n = (float)counts[g];
            const float nn = fmaxf(n, 1.0f);
            const float logdet = ld[g] + (nn - (float)D) * log_diag;
            const float tcr = 0.5f * logdet;
            const float def = fmaxf(min_tcr - tcr, 0.0f);
            if (counts[g] >= MINS) { s[g / NC] += def; c2[g / NC] += 1.0f; }
        }
        float avg = 0.0f;
        for (int b = 0; b < 2; ++b)
            avg += (c2[b] > 0.0f) ? s[b] / fmaxf(c2[b], 1.0f) : 0.0f;
        avg *= 0.5f;
        out[0] = 1.0f * 0.05f * avg;
    }
}

extern "C" void kernel_launch(void* const* d_in, const int* in_sizes, int n_in,
                              void* d_out, int out_size, void* d_ws, size_t ws_size,
                              hipStream_t stream) {
    const int*   target = (const int*)d_in[1];
    const float* feat   = (const float*)d_in[2];
    const int*   batch  = (const int*)d_in[3];
    float* out = (float*)d_out;
    char* ws = (char*)d_ws;
    const int n = in_sizes[1];

    int*   counts = (int*)(ws + OFF_CNT);
    int*   offs   = (int*)(ws + OFF_OFFS);
    float* logdet = (float*)(ws + OFF_LOGDET);
    int*   hist   = (int*)(ws + OFF_HIST);
    int*   idxbuf = (int*)(ws + OFF_IDX);
    float* rnorm  = (float*)(ws + OFF_RNORM);
    float* gram   = (float*)(ws + OFF_GRAM);

    long avail = (long)ws_size - (long)OFF_PART;
    int CH;
    float* part;
    bool need_reduce;
    if (avail >= (long)GRAM_BYTES) {
        long c = avail / (long)GRAM_BYTES;
        CH = (int)(c < 8 ? c : 8);
        part = (float*)(ws + OFF_PART);
        need_reduce = true;
    } else {
        CH = 1;
        part = gram;
        need_reduce = false;
    }

    const int NB = (n + 255) / 256;

    k_norm    <<<(n + 3) / 4, 256, 0, stream>>>(feat, rnorm, n);
    k_hist    <<<NB, 256, 0, stream>>>(target, batch, hist, n);
    k_prefix2 <<<1, 256, 0, stream>>>(hist, counts, offs, NB);
    k_scatter2<<<NB, 256, 0, stream>>>(target, batch, hist, idxbuf, n);
    k_gram    <<<dim3(3, G, CH), 256, 0, stream>>>(feat, rnorm, idxbuf, counts, offs, part);
    if (need_reduce)
        k_reduce<<<256, 256, 0, stream>>>(part, gram, CH);
    k_chol    <<<G, 512, 0, stream>>>(gram, counts, logdet);
    k_final   <<<1, 64, 0, stream>>>(logdet, counts, out);
}

// Round 5
// 67.469 us; speedup vs baseline: 16.8338x; 4.3158x over previous
//
#include <hip/hip_runtime.h>
#include <math.h>

#define D 256
#define NC 8
#define G 16
#define MINS 10
#define CS 512

// ---- workspace layout (bytes) ----
#define OFF_CNT     0u
#define OFF_OFFS    128u
#define OFF_LOGDET  256u
#define OFF_NEED    512u
#define OFF_HIST    1024u                            // NB*16 ints (<=16KB)
#define OFF_NZH     17408u                           // NB*16 ints (<=16KB)
#define OFF_IDX     33792u                           // 256KB
#define OFF_NZF     295936u                          // 64KB (byte per row)
#define OFF_RNORM   361472u                          // 256KB
#define OFF_GRAM    (1u<<20)                         // 1 MB
#define GRAM_BYTES  (G*D*D*4u)                       // 4 MB
#define OFF_PART    (OFF_GRAM + GRAM_BYTES)          // 5 MB

// row norms + nonzero flag (certificate input). 4 rows/block, 64 lanes/row.
__global__ void k_norm(const float* __restrict__ feat, float* __restrict__ rnorm,
                       unsigned char* __restrict__ nzflag, int n) {
    int row = blockIdx.x * 4 + (threadIdx.x >> 6);
    if (row >= n) return;
    int lane = threadIdx.x & 63;
    const float4 v = *(const float4*)(feat + (size_t)row * D + lane * 4);
    float s = v.x*v.x + v.y*v.y + v.z*v.z + v.w*v.w;
    #pragma unroll
    for (int d = 32; d; d >>= 1) s += __shfl_xor(s, d, 64);
    if (lane == 0) {
        rnorm[row] = 1.0f / fmaxf(sqrtf(s), 1e-12f);
        nzflag[row] = (s >= 1e-24f) ? 1 : 0;   // ||x|| >= 1e-12
    }
}

__device__ __forceinline__ int group_of(int t, int b) {
    t = t < 0 ? 0 : (t > NC - 1 ? NC - 1 : t);
    return b * NC + t;
}

// ---- pass 1: per-block 16-bin histograms (count + nonzero count), no atomics ----
__global__ __launch_bounds__(256) void k_hist(
    const int* __restrict__ target, const int* __restrict__ batch,
    const unsigned char* __restrict__ nzflag,
    int* __restrict__ hist, int* __restrict__ nzhist, int n) {
    __shared__ unsigned short wcnt[4][G];
    __shared__ unsigned short wnz[4][G];
    const int tid = threadIdx.x;
    const int i = blockIdx.x * 256 + tid;
    const int wave = tid >> 6, lane = tid & 63;
    const bool valid = i < n;
    const int g = valid ? group_of(target[i], batch[i]) : -1;
    const bool nz = valid ? (nzflag[i] != 0) : false;
    #pragma unroll
    for (int gv = 0; gv < G; ++gv) {
        unsigned long long m  = __ballot(g == gv);
        unsigned long long mz = __ballot(g == gv && nz);
        if (lane == 0) {
            wcnt[wave][gv] = (unsigned short)__popcll(m);
            wnz[wave][gv]  = (unsigned short)__popcll(mz);
        }
    }
    __syncthreads();
    if (tid < G) {
        hist[blockIdx.x * G + tid] =
            (int)wcnt[0][tid] + wcnt[1][tid] + wcnt[2][tid] + wcnt[3][tid];
        nzhist[blockIdx.x * G + tid] =
            (int)wnz[0][tid] + wnz[1][tid] + wnz[2][tid] + wnz[3][tid];
    }
}

// ---- pass 2: prefix over blocks per group, group offsets, certificate ----
// cert: logdet(aG+(1+eps)I) >= log(1 + a*tr(G)) >= log(1 + a*nz) ; deficit==0
// guaranteed when a*nz >= 512 (2x margin over exact threshold D-1=255).
__global__ __launch_bounds__(256) void k_prefix2(
    int* __restrict__ hist, const int* __restrict__ nzhist,
    int* __restrict__ counts, int* __restrict__ offs, int* __restrict__ need, int NB) {
    __shared__ int h[256 * G];
    __shared__ int soffs[G];
    const int tid = threadIdx.x;
    for (int e = tid; e < NB * G; e += 256) h[e] = hist[e];
    __syncthreads();
    if (tid < G) {
        int run = 0;
        for (int b = 0; b < NB; ++b) {
            const int v = h[b * G + tid];
            h[b * G + tid] = run;
            run += v;
        }
        counts[tid] = run;
        int nz = 0;
        for (int b = 0; b < NB; ++b) nz += nzhist[b * G + tid];
        const float nn = fmaxf((float)run, 1.0f);
        const float aa = (float)D / (nn * 0.04f);        // D/(n*eps^2)
        need[tid] = (aa * (float)nz < 512.0f) ? 1 : 0;   // fallback only if cert fails
    }
    __syncthreads();
    if (tid == 0) {
        int o = 0;
        for (int gv = 0; gv < G; ++gv) { soffs[gv] = o; offs[gv] = o; o += counts[gv]; }
    }
    __syncthreads();
    for (int e = tid; e < NB * G; e += 256) hist[e] = h[e] + soffs[e & (G - 1)];
}

// ---- pass 3: deterministic rank-based scatter; stores only for fallback groups ----
__global__ __launch_bounds__(256) void k_scatter2(
    const int* __restrict__ target, const int* __restrict__ batch,
    const int* __restrict__ base, const int* __restrict__ need,
    int* __restrict__ idxbuf, int n) {
    __shared__ int wbase[4][G];
    __shared__ unsigned short wcnt[4][G];
    __shared__ int sneed[G];
    const int tid = threadIdx.x;
    const int i = blockIdx.x * 256 + tid;
    const int wave = tid >> 6, lane = tid & 63;
    const bool valid = i < n;
    const int g = valid ? group_of(target[i], batch[i]) : -1;
    if (tid < G) sneed[tid] = need[tid];
    int rank = 0;
    #pragma unroll
    for (int gv = 0; gv < G; ++gv) {
        unsigned long long m = __ballot(g == gv);
        if (g == gv) rank = __popcll(m & ((1ull << lane) - 1ull));
        if (lane == 0) wcnt[wave][gv] = (unsigned short)__popcll(m);
    }
    __syncthreads();
    if (tid < G) {
        int run = base[blockIdx.x * G + tid];
        #pragma unroll
        for (int w = 0; w < 4; ++w) { wbase[w][tid] = run; run += wcnt[w][tid]; }
    }
    __syncthreads();
    if (valid && sneed[g]) idxbuf[wbase[wave][g] + rank] = i;
}

// grouped split-K SYRK (fallback path; early-exits for certified groups)
__global__ __launch_bounds__(256) void k_gram(
    const float* __restrict__ feat, const float* __restrict__ rnorm,
    const int* __restrict__ idxbuf, const int* __restrict__ counts,
    const int* __restrict__ offs, const int* __restrict__ need,
    float* __restrict__ part) {
    const int p  = blockIdx.x;
    const int g  = blockIdx.y;
    if (!need[g]) return;
    const int slot = blockIdx.z;
    const int CH = gridDim.z;
    const int ti = (p >= 1) ? 1 : 0, tj = (p == 2) ? 1 : 0;
    const int n = counts[g], off = offs[g];

    __shared__ float LA[32][132];
    __shared__ float LB[32][132];

    const int tid = threadIdx.x;
    const int ty = tid >> 4, tx = tid & 15;
    const int rr = tid >> 3, seg = tid & 7;

    float acc[8][8];
    #pragma unroll
    for (int i = 0; i < 8; ++i)
        #pragma unroll
        for (int j = 0; j < 8; ++j) acc[i][j] = 0.0f;

    for (int c = slot; c * CS < n; c += CH) {
        const int cbase = c * CS;
        const int cend  = (cbase + CS < n) ? cbase + CS : n;
        for (int sub = cbase; sub < cend; sub += 32) {
            const int r = sub + rr;
            const bool valid = (r < cend);
            const int row = valid ? idxbuf[off + r] : 0;
            const float inv = valid ? rnorm[row] : 0.0f;
            const float* bA = feat + (size_t)row * D + ti * 128 + seg * 16;
            float4 va[4], vb[4];
            #pragma unroll
            for (int q = 0; q < 4; ++q) {
                float4 v = *(const float4*)(bA + q * 4);
                v.x *= inv; v.y *= inv; v.z *= inv; v.w *= inv;
                va[q] = v;
            }
            if (p == 1) {
                const float* bB = feat + (size_t)row * D + seg * 16;
                #pragma unroll
                for (int q = 0; q < 4; ++q) {
                    float4 v = *(const float4*)(bB + q * 4);
                    v.x *= inv; v.y *= inv; v.z *= inv; v.w *= inv;
                    vb[q] = v;
                }
            }
            __syncthreads();
            #pragma unroll
            for (int q = 0; q < 4; ++q)
                *(float4*)&LA[rr][seg * 16 + q * 4] = va[q];
            if (p == 1) {
                #pragma unroll
                for (int q = 0; q < 4; ++q)
                    *(float4*)&LB[rr][seg * 16 + q * 4] = vb[q];
            }
            __syncthreads();

            const float (*Bt)[132] = (p == 1) ? LB : LA;
            #pragma unroll 4
            for (int r2 = 0; r2 < 32; ++r2) {
                const float* Ar = &LA[r2][0];
                const float* Br = &Bt[r2][0];
                float4 a0 = *(const float4*)(Ar + ty * 8);
                float4 a1 = *(const float4*)(Ar + ty * 8 + 4);
                float4 b0 = *(const float4*)(Br + tx * 4);
                float4 b1 = *(const float4*)(Br + 64 + tx * 4);
                float av[8] = {a0.x,a0.y,a0.z,a0.w,a1.x,a1.y,a1.z,a1.w};
                float bv[8] = {b0.x,b0.y,b0.z,b0.w,b1.x,b1.y,b1.z,b1.w};
                #pragma unroll
                for (int i = 0; i < 8; ++i)
                    #pragma unroll
                    for (int j = 0; j < 8; ++j)
                        acc[i][j] = fmaf(av[i], bv[j], acc[i][j]);
            }
        }
    }

    float* base = part + ((size_t)slot * G + g) * (D * D);
    #pragma unroll
    for (int i = 0; i < 8; ++i) {
        const int row_g = ti * 128 + ty * 8 + i;
        float4 lo = {acc[i][0], acc[i][1], acc[i][2], acc[i][3]};
        float4 hi = {acc[i][4], acc[i][5], acc[i][6], acc[i][7]};
        *(float4*)(base + (size_t)row_g * D + tj * 128 + tx * 4)      = lo;
        *(float4*)(base + (size_t)row_g * D + tj * 128 + 64 + tx * 4) = hi;
    }
    if (p == 1) {
        #pragma unroll
        for (int j = 0; j < 8; ++j) {
            const int col_g = (j < 4) ? (tx * 4 + j) : (64 + tx * 4 + (j - 4));
            float4 lo = {acc[0][j], acc[1][j], acc[2][j], acc[3][j]};
            float4 hi = {acc[4][j], acc[5][j], acc[6][j], acc[7][j]};
            float* dst = base + (size_t)col_g * D + 128 + ty * 8;
            *(float4*)dst       = lo;
            *(float4*)(dst + 4) = hi;
        }
    }
}

__global__ void k_reduce(const float* __restrict__ part, float* __restrict__ gram,
                         const int* __restrict__ need, int CH) {
    const int total4 = G * D * D / 4;
    const float4* p4 = (const float4*)part;
    float4* g4 = (float4*)gram;
    for (int e = blockIdx.x * blockDim.x + threadIdx.x; e < total4; e += gridDim.x * blockDim.x) {
        const int gg = e >> 14;           // e / (D*D/4)
        if (!need[gg]) continue;
        float4 s = p4[e];
        for (int ch = 1; ch < CH; ++ch) {
            float4 t = p4[(size_t)ch * total4 + e];
            s.x += t.x; s.y += t.y; s.z += t.z; s.w += t.w;
        }
        g4[e] = s;
    }
}

// packed-lower-triangle row offset, rows padded to 4 floats
__device__ __forceinline__ int rowoff(int i) {
    int q = i >> 2, s = i & 3;
    return 4 * (2 * q * (q + 1) + s * (q + 1));
}

__device__ __forceinline__ void factor_diag(
    float* T, float (*L11c)[16], float* invdb, int kb16, int lane, float& plog) {
    const int r = kb16 + lane;
    float rr[16];
    const float* Tr = T + rowoff(r);
    #pragma unroll
    for (int q = 0; q < 4; ++q) {
        if (kb16 + q * 4 <= r) {
            float4 v = *(const float4*)(Tr + kb16 + q * 4);
            rr[q*4+0] = v.x; rr[q*4+1] = v.y; rr[q*4+2] = v.z; rr[q*4+3] = v.w;
        } else {
            rr[q*4+0] = 0.0f; rr[q*4+1] = 0.0f; rr[q*4+2] = 0.0f; rr[q*4+3] = 0.0f;
        }
    }
    float mypiv = 1.0f, myinv = 1.0f;
    #pragma unroll
    for (int pc = 0; pc < 16; ++pc) {
        const float piv = __shfl(rr[pc], pc);
        const float inv = 1.0f / sqrtf(piv);
        mypiv = (lane == pc) ? piv : mypiv;
        myinv = (lane == pc) ? inv : myinv;
        if (lane > pc) rr[pc] *= inv;
        #pragma unroll
        for (int j = pc + 1; j < 16; ++j) {
            const float Lj = __shfl(rr[pc], j);
            if (lane >= j) rr[j] = fmaf(-rr[pc], Lj, rr[j]);
        }
    }
    plog += __logf(mypiv);
    invdb[lane] = myinv;
    #pragma unroll
    for (int pp = 0; pp < 16; ++pp)
        if (pp < lane) L11c[pp][lane] = rr[pp];
}

// fallback blocked Cholesky (early-exits for certified groups)
__global__ __launch_bounds__(512) void k_chol(
    const float* __restrict__ gram, const int* __restrict__ counts,
    const int* __restrict__ need, float* __restrict__ logdetbuf) {
    const int g = blockIdx.x;
    if (!need[g]) return;
    const int tid = threadIdx.x;
    __shared__ float T[33280];
    __shared__ float PT[16 * 256];
    __shared__ float L11c[2][16][16];
    __shared__ float invdb[2][16];
    __shared__ int tctr;

    const int n = counts[g];
    const float nn = fmaxf((float)n, 1.0f);
    const float aa = (float)D / (nn * 0.04f);
    const float dg = 1.0f + 1e-6f;

    {
        const int r = tid >> 1, half = tid & 1;
        const int nch = (r >> 2) + 1;
        const int mid = (nch + 1) >> 1;
        const int clo = half ? mid : 0;
        const int chi = half ? nch : mid;
        const float* Gr = gram + (size_t)g * (D * D) + (size_t)r * D;
        float* Tr = T + rowoff(r);
        for (int c = clo; c < chi; ++c) {
            float4 v = *(const float4*)(Gr + c * 4);
            v.x *= aa; v.y *= aa; v.z *= aa; v.w *= aa;
            v.x += (c * 4 + 0 == r) ? dg : 0.0f;
            v.y += (c * 4 + 1 == r) ? dg : 0.0f;
            v.z += (c * 4 + 2 == r) ? dg : 0.0f;
            v.w += (c * 4 + 3 == r) ? dg : 0.0f;
            *(float4*)(Tr + c * 4) = v;
        }
    }
    __syncthreads();

    float plog = 0.0f;
    const int wave = tid >> 6;
    const int lane = tid & 63;
    const int li = lane >> 3, lj = lane & 7;

    if (tid < 16) factor_diag(T, L11c[0], invdb[0], 0, tid, plog);
    __syncthreads();

    for (int kb = 0; kb < 15; ++kb) {
        const int kb16 = kb * 16;
        const int par = kb & 1;
        const int pstart = kb16 + 16;
        const int R = 256 - pstart;

        if (tid < R) {
            const int r = pstart + tid;
            const float* Tr = T + rowoff(r) + kb16;
            float x[16];
            {
                float4 v0 = *(const float4*)(Tr + 0);
                float4 v1 = *(const float4*)(Tr + 4);
                float4 v2 = *(const float4*)(Tr + 8);
                float4 v3 = *(const float4*)(Tr + 12);
                x[0]=v0.x; x[1]=v0.y; x[2]=v0.z; x[3]=v0.w;
                x[4]=v1.x; x[5]=v1.y; x[6]=v1.z; x[7]=v1.w;
                x[8]=v2.x; x[9]=v2.y; x[10]=v2.z; x[11]=v2.w;
                x[12]=v3.x; x[13]=v3.y; x[14]=v3.z; x[15]=v3.w;
            }
            float iv[16];
            {
                const float* ivp = invdb[par];
                float4 i0 = *(const float4*)(ivp + 0);
                float4 i1 = *(const float4*)(ivp + 4);
                float4 i2 = *(const float4*)(ivp + 8);
                float4 i3 = *(const float4*)(ivp + 12);
                iv[0]=i0.x; iv[1]=i0.y; iv[2]=i0.z; iv[3]=i0.w;
                iv[4]=i1.x; iv[5]=i1.y; iv[6]=i1.z; iv[7]=i1.w;
                iv[8]=i2.x; iv[9]=i2.y; iv[10]=i2.z; iv[11]=i2.w;
                iv[12]=i3.x; iv[13]=i3.y; iv[14]=i3.z; iv[15]=i3.w;
            }
            const float (*Lc)[16] = L11c[par];
            float4 n0 = *(const float4*)&Lc[0][0];
            float4 n1 = *(const float4*)&Lc[0][4];
            float4 n2 = *(const float4*)&Lc[0][8];
            float4 n3 = *(const float4*)&Lc[0][12];
            #pragma unroll
            for (int c = 0; c < 16; ++c) {
                const float col[16] = {n0.x,n0.y,n0.z,n0.w, n1.x,n1.y,n1.z,n1.w,
                                       n2.x,n2.y,n2.z,n2.w, n3.x,n3.y,n3.z,n3.w};
                if (c < 15) {
                    n0 = *(const float4*)&Lc[c+1][0];
                    n1 = *(const float4*)&Lc[c+1][4];
                    n2 = *(const float4*)&Lc[c+1][8];
                    n3 = *(const float4*)&Lc[c+1][12];
                }
                const float xc = x[c] * iv[c];
                x[c] = xc;
                #pragma unroll
                for (int j = 0; j < 16; ++j)
                    if (j > c) x[j] = fmaf(-xc, col[j], x[j]);
            }
            #pragma unroll
            for (int pp = 0; pp < 16; ++pp)
                PT[pp * 256 + r] = x[pp];
        }
        if (tid == 0) tctr = 1;
        __syncthreads();

        const int MRm = (R + 31) >> 5;
        const int nmac = MRm * (MRm + 1) / 2;

        auto do_tile = [&](int idx) {
            int MI = 0, base = 0;
            while (base + MI + 1 <= idx) { base += MI + 1; ++MI; }
            const int MJ = idx - base;
            const int r0 = pstart + MI * 32 + li * 4;
            const int c0 = pstart + MJ * 32 + lj * 4;
            if (r0 >= 256 || c0 >= 256) return;
            if (c0 > r0 + 3) return;
            float acc[4][4];
            #pragma unroll
            for (int qi = 0; qi < 4; ++qi)
                #pragma unroll
                for (int qj = 0; qj < 4; ++qj) acc[qi][qj] = 0.0f;
            #pragma unroll
            for (int pq = 0; pq < 4; ++pq) {
                float4 a[4], b[4];
                #pragma unroll
                for (int q = 0; q < 4; ++q) {
                    a[q] = *(const float4*)&PT[(pq * 4 + q) * 256 + r0];
                    b[q] = *(const float4*)&PT[(pq * 4 + q) * 256 + c0];
                }
                #pragma unroll
                for (int q = 0; q < 4; ++q) {
                    float a4[4] = {a[q].x, a[q].y, a[q].z, a[q].w};
                    float b4[4] = {b[q].x, b[q].y, b[q].z, b[q].w};
                    #pragma unroll
                    for (int qi = 0; qi < 4; ++qi)
                        #pragma unroll
                        for (int qj = 0; qj < 4; ++qj)
                            acc[qi][qj] = fmaf(a4[qi], b4[qj], acc[qi][qj]);
                }
            }
            #pragma unroll
            for (int qi = 0; qi < 4; ++qi) {
                const int r = r0 + qi;
                float* cp = T + rowoff(r) + c0;
                if (c0 + 3 <= r) {
                    float4 t = *(float4*)cp;
                    t.x -= acc[qi][0]; t.y -= acc[qi][1];
                    t.z -= acc[qi][2]; t.w -= acc[qi][3];
                    *(float4*)cp = t;
                } else {
                    #pragma unroll
                    for (int qj = 0; qj < 4; ++qj)
                        if (c0 + qj <= r) cp[qj] -= acc[qi][qj];
                }
            }
        };

        if (wave == 0) {
            do_tile(0);
            if (lane < 16)
                factor_diag(T, L11c[par ^ 1], invdb[par ^ 1], pstart, lane, plog);
        }
        int grab;
        if (lane == 0) grab = atomicAdd(&tctr, 1);
        grab = __shfl(grab, 0);
        while (grab < nmac) {
            do_tile(grab);
            if (lane == 0) grab = atomicAdd(&tctr, 1);
            grab = __shfl(grab, 0);
        }
        __syncthreads();
    }

    if (tid < 16) {
        #pragma unroll
        for (int d = 8; d; d >>= 1) plog += __shfl_xor(plog, d);
        if (tid == 0) logdetbuf[g] = plog;
    }
}

__global__ void k_final(const float* __restrict__ ld, const int* __restrict__ counts,
                        const int* __restrict__ need, float* __restrict__ out) {
    if (threadIdx.x == 0 && blockIdx.x == 0) {
        const float min_tcr = 0.5f * logf(256.0f);
        const float log_diag = logf(1.0f + 1e-6f + 1e-12f);
        float s[2] = {0.0f, 0.0f}, c2[2] = {0.0f, 0.0f};
        for (int g = 0; g < G; ++g) {
            if (counts[g] < MINS) continue;
            float def = 0.0f;                   // certified: deficit exactly 0
            if (need[g]) {
                const float n = (float)counts[g];
                const float nn = fmaxf(n, 1.0f);
                const float logdet = ld[g] + (nn - (float)D) * log_diag;
                const float tcr = 0.5f * logdet;
                def = fmaxf(min_tcr - tcr, 0.0f);
            }
            s[g / NC] += def; c2[g / NC] += 1.0f;
        }
        float avg = 0.0f;
        for (int b = 0; b < 2; ++b)
            avg += (c2[b] > 0.0f) ? s[b] / fmaxf(c2[b], 1.0f) : 0.0f;
        avg *= 0.5f;
        out[0] = 1.0f * 0.05f * avg;
    }
}

extern "C" void kernel_launch(void* const* d_in, const int* in_sizes, int n_in,
                              void* d_out, int out_size, void* d_ws, size_t ws_size,
                              hipStream_t stream) {
    const int*   target = (const int*)d_in[1];
    const float* feat   = (const float*)d_in[2];
    const int*   batch  = (const int*)d_in[3];
    float* out = (float*)d_out;
    char* ws = (char*)d_ws;
    const int n = in_sizes[1];

    int*   counts = (int*)(ws + OFF_CNT);
    int*   offs   = (int*)(ws + OFF_OFFS);
    float* logdet = (float*)(ws + OFF_LOGDET);
    int*   need   = (int*)(ws + OFF_NEED);
    int*   hist   = (int*)(ws + OFF_HIST);
    int*   nzhist = (int*)(ws + OFF_NZH);
    int*   idxbuf = (int*)(ws + OFF_IDX);
    unsigned char* nzflag = (unsigned char*)(ws + OFF_NZF);
    float* rnorm  = (float*)(ws + OFF_RNORM);
    float* gram   = (float*)(ws + OFF_GRAM);

    long avail = (long)ws_size - (long)OFF_PART;
    int CH;
    float* part;
    bool need_reduce;
    if (avail >= (long)GRAM_BYTES) {
        long c = avail / (long)GRAM_BYTES;
        CH = (int)(c < 8 ? c : 8);
        part = (float*)(ws + OFF_PART);
        need_reduce = true;
    } else {
        CH = 1;
        part = gram;
        need_reduce = false;
    }

    const int NB = (n + 255) / 256;

    k_norm    <<<(n + 3) / 4, 256, 0, stream>>>(feat, rnorm, nzflag, n);
    k_hist    <<<NB, 256, 0, stream>>>(target, batch, nzflag, hist, nzhist, n);
    k_prefix2 <<<1, 256, 0, stream>>>(hist, nzhist, counts, offs, need, NB);
    k_scatter2<<<NB, 256, 0, stream>>>(target, batch, hist, need, idxbuf, n);
    k_gram    <<<dim3(3, G, CH), 256, 0, stream>>>(feat, rnorm, idxbuf, counts, offs, need, part);
    if (need_reduce)
        k_reduce<<<256, 256, 0, stream>>>(part, gram, need, CH);
    k_chol    <<<G, 512, 0, stream>>>(gram, counts, need, logdet);
    k_final   <<<1, 64, 0, stream>>>(logdet, counts, need, out);
}

// Round 6
// 33.102 us; speedup vs baseline: 34.3116x; 2.0383x over previous
//
#include <hip/hip_runtime.h>
#include <math.h>

#define D 256
#define NC 8
#define G 16
#define MINS 10
#define CS 512
#define NBH 64            // histogram/scatter blocks (compile-time for unrolled scans)

// ---- workspace layout (bytes) ----
#define OFF_CNT     0u
#define OFF_OFFS    128u
#define OFF_LOGDET  256u
#define OFF_NEED    512u     // G ints + [G] = anyneed flag
#define OFF_CTR     640u
#define OFF_HIST    1024u    // NBH*G ints (4KB)
#define OFF_NZH     8192u    // NBH*G ints (4KB)
#define OFF_IDX     16384u   // 256KB
#define OFF_NZF     278528u  // 64KB (byte per row)
#define OFF_RNORM   344064u  // 256KB
#define OFF_GRAM    (1u<<20) // 1MB: CH slots of 4MB each start here
#define GRAM_BYTES  (G*D*D*4u)

// row norms + nonzero flag (certificate input). 4 rows/block, 64 lanes/row.
__global__ void k_norm(const float* __restrict__ feat, float* __restrict__ rnorm,
                       unsigned char* __restrict__ nzflag, int n) {
    int row = blockIdx.x * 4 + (threadIdx.x >> 6);
    if (row >= n) return;
    int lane = threadIdx.x & 63;
    const float4 v = *(const float4*)(feat + (size_t)row * D + lane * 4);
    float s = v.x*v.x + v.y*v.y + v.z*v.z + v.w*v.w;
    #pragma unroll
    for (int d = 32; d; d >>= 1) s += __shfl_xor(s, d, 64);
    if (lane == 0) {
        rnorm[row] = 1.0f / fmaxf(sqrtf(s), 1e-12f);
        nzflag[row] = (s >= 1e-24f) ? 1 : 0;   // ||x|| >= 1e-12
    }
}

__device__ __forceinline__ int group_of(int t, int b) {
    t = t < 0 ? 0 : (t > NC - 1 ? NC - 1 : t);
    return b * NC + t;
}

// ---- pass 1: per-block histograms (count + nz count) via ballots, no atomics ----
// block b processes chunks [b*cpb, min((b+1)*cpb, chunks)), 256 elems/chunk.
__global__ __launch_bounds__(256) void k_hist(
    const int* __restrict__ target, const int* __restrict__ batch,
    const unsigned char* __restrict__ nzflag,
    int* __restrict__ hist, int* __restrict__ nzhist, int n, int cpb, int chunks) {
    __shared__ int sc[4][G], sn[4][G];
    const int tid = threadIdx.x;
    const int wave = tid >> 6, lane = tid & 63;
    int myc = 0, mynz = 0;
    const int c0 = blockIdx.x * cpb;
    const int c1 = min(c0 + cpb, chunks);
    for (int c = c0; c < c1; ++c) {
        const int i = c * 256 + tid;
        const bool valid = i < n;
        const int g = valid ? group_of(target[i], batch[i]) : -1;
        const bool nz = valid && (nzflag[i] != 0);
        #pragma unroll
        for (int gv = 0; gv < G; ++gv) {
            unsigned long long m  = __ballot(g == gv);
            unsigned long long mz = __ballot(g == gv && nz);
            if (lane == gv) { myc += __popcll(m); mynz += __popcll(mz); }
        }
    }
    if (lane < G) { sc[wave][lane] = myc; sn[wave][lane] = mynz; }
    __syncthreads();
    if (tid < G) {
        hist[blockIdx.x * G + tid]   = sc[0][tid] + sc[1][tid] + sc[2][tid] + sc[3][tid];
        nzhist[blockIdx.x * G + tid] = sn[0][tid] + sn[1][tid] + sn[2][tid] + sn[3][tid];
    }
}

// ---- pass 2: prefix over NBH blocks per group, offsets, certificate, ctr reset ----
// cert: logdet(aG+(1+eps)I) >= log(1 + a*nz); deficit==0 guaranteed when a*nz>=512
// (2x margin over exact threshold D-1=255).
__global__ __launch_bounds__(256) void k_prefix2(
    int* __restrict__ hist, const int* __restrict__ nzhist,
    int* __restrict__ counts, int* __restrict__ offs, int* __restrict__ need,
    int* __restrict__ ctr) {
    __shared__ int h[NBH * G];
    __shared__ int hn[NBH * G];
    __shared__ int soffs[G];
    __shared__ int sneed[G];
    const int tid = threadIdx.x;
    #pragma unroll
    for (int e = tid; e < NBH * G; e += 256) { h[e] = hist[e]; hn[e] = nzhist[e]; }
    __syncthreads();
    if (tid < G) {
        int run = 0;
        #pragma unroll
        for (int b = 0; b < NBH; ++b) {
            const int v = h[b * G + tid];
            h[b * G + tid] = run;
            run += v;
        }
        counts[tid] = run;
        int nz = 0;
        #pragma unroll
        for (int b = 0; b < NBH; ++b) nz += hn[b * G + tid];
        const float nn = fmaxf((float)run, 1.0f);
        const float aa = (float)D / (nn * 0.04f);        // D/(n*eps^2)
        const int nd = (aa * (float)nz < 512.0f) ? 1 : 0;
        need[tid] = nd; sneed[tid] = nd;
    }
    __syncthreads();
    if (tid == 0) {
        int o = 0, anyf = 0;
        for (int gv = 0; gv < G; ++gv) {
            soffs[gv] = o; offs[gv] = o; o += counts[gv];
            anyf |= sneed[gv];
        }
        need[G] = anyf;
        ctr[0] = 0;
    }
    __syncthreads();
    #pragma unroll
    for (int e = tid; e < NBH * G; e += 256) hist[e] = h[e] + soffs[e & (G - 1)];
}

// ---- pass 3: deterministic rank scatter; whole-grid early-exit when certified ----
__global__ __launch_bounds__(256) void k_scatter2(
    const int* __restrict__ target, const int* __restrict__ batch,
    const int* __restrict__ base, const int* __restrict__ need,
    int* __restrict__ idxbuf, int n, int cpb, int chunks) {
    __shared__ int anyf_s;
    const int tid = threadIdx.x;
    if (tid == 0) anyf_s = need[G];
    __syncthreads();
    if (!anyf_s) return;

    __shared__ int cursor[G];
    __shared__ int wb[4][G];
    __shared__ int wc[4][G];
    __shared__ int sneed[G];
    const int wave = tid >> 6, lane = tid & 63;
    if (tid < G) { cursor[tid] = base[blockIdx.x * G + tid]; sneed[tid] = need[tid]; }
    __syncthreads();

    const int c0 = blockIdx.x * cpb;
    const int c1 = min(c0 + cpb, chunks);
    for (int c = c0; c < c1; ++c) {
        const int i = c * 256 + tid;
        const bool valid = i < n;
        const int g = valid ? group_of(target[i], batch[i]) : -1;
        int rank = 0;
        #pragma unroll
        for (int gv = 0; gv < G; ++gv) {
            unsigned long long m = __ballot(g == gv);
            if (g == gv) rank = __popcll(m & ((1ull << lane) - 1ull));
            if (lane == 0) wc[wave][gv] = __popcll(m);
        }
        __syncthreads();
        if (tid < G) {
            int run = cursor[tid];
            #pragma unroll
            for (int w = 0; w < 4; ++w) { wb[w][tid] = run; run += wc[w][tid]; }
            cursor[tid] = run;
        }
        __syncthreads();
        if (valid && sneed[g]) idxbuf[wb[wave][g] + rank] = i;
    }
}

// grouped split-K SYRK (fallback path; early-exits for certified groups)
__global__ __launch_bounds__(256) void k_gram(
    const float* __restrict__ feat, const float* __restrict__ rnorm,
    const int* __restrict__ idxbuf, const int* __restrict__ counts,
    const int* __restrict__ offs, const int* __restrict__ need,
    float* __restrict__ part) {
    const int p  = blockIdx.x;
    const int g  = blockIdx.y;
    if (!need[g]) return;
    const int slot = blockIdx.z;
    const int CH = gridDim.z;
    const int ti = (p >= 1) ? 1 : 0, tj = (p == 2) ? 1 : 0;
    const int n = counts[g], off = offs[g];

    __shared__ float LA[32][132];
    __shared__ float LB[32][132];

    const int tid = threadIdx.x;
    const int ty = tid >> 4, tx = tid & 15;
    const int rr = tid >> 3, seg = tid & 7;

    float acc[8][8];
    #pragma unroll
    for (int i = 0; i < 8; ++i)
        #pragma unroll
        for (int j = 0; j < 8; ++j) acc[i][j] = 0.0f;

    for (int c = slot; c * CS < n; c += CH) {
        const int cbase = c * CS;
        const int cend  = (cbase + CS < n) ? cbase + CS : n;
        for (int sub = cbase; sub < cend; sub += 32) {
            const int r = sub + rr;
            const bool valid = (r < cend);
            const int row = valid ? idxbuf[off + r] : 0;
            const float inv = valid ? rnorm[row] : 0.0f;
            const float* bA = feat + (size_t)row * D + ti * 128 + seg * 16;
            float4 va[4], vb[4];
            #pragma unroll
            for (int q = 0; q < 4; ++q) {
                float4 v = *(const float4*)(bA + q * 4);
                v.x *= inv; v.y *= inv; v.z *= inv; v.w *= inv;
                va[q] = v;
            }
            if (p == 1) {
                const float* bB = feat + (size_t)row * D + seg * 16;
                #pragma unroll
                for (int q = 0; q < 4; ++q) {
                    float4 v = *(const float4*)(bB + q * 4);
                    v.x *= inv; v.y *= inv; v.z *= inv; v.w *= inv;
                    vb[q] = v;
                }
            }
            __syncthreads();
            #pragma unroll
            for (int q = 0; q < 4; ++q)
                *(float4*)&LA[rr][seg * 16 + q * 4] = va[q];
            if (p == 1) {
                #pragma unroll
                for (int q = 0; q < 4; ++q)
                    *(float4*)&LB[rr][seg * 16 + q * 4] = vb[q];
            }
            __syncthreads();

            const float (*Bt)[132] = (p == 1) ? LB : LA;
            #pragma unroll 4
            for (int r2 = 0; r2 < 32; ++r2) {
                const float* Ar = &LA[r2][0];
                const float* Br = &Bt[r2][0];
                float4 a0 = *(const float4*)(Ar + ty * 8);
                float4 a1 = *(const float4*)(Ar + ty * 8 + 4);
                float4 b0 = *(const float4*)(Br + tx * 4);
                float4 b1 = *(const float4*)(Br + 64 + tx * 4);
                float av[8] = {a0.x,a0.y,a0.z,a0.w,a1.x,a1.y,a1.z,a1.w};
                float bv[8] = {b0.x,b0.y,b0.z,b0.w,b1.x,b1.y,b1.z,b1.w};
                #pragma unroll
                for (int i = 0; i < 8; ++i)
                    #pragma unroll
                    for (int j = 0; j < 8; ++j)
                        acc[i][j] = fmaf(av[i], bv[j], acc[i][j]);
            }
        }
    }

    float* base = part + ((size_t)slot * G + g) * (D * D);
    #pragma unroll
    for (int i = 0; i < 8; ++i) {
        const int row_g = ti * 128 + ty * 8 + i;
        float4 lo = {acc[i][0], acc[i][1], acc[i][2], acc[i][3]};
        float4 hi = {acc[i][4], acc[i][5], acc[i][6], acc[i][7]};
        *(float4*)(base + (size_t)row_g * D + tj * 128 + tx * 4)      = lo;
        *(float4*)(base + (size_t)row_g * D + tj * 128 + 64 + tx * 4) = hi;
    }
    if (p == 1) {
        #pragma unroll
        for (int j = 0; j < 8; ++j) {
            const int col_g = (j < 4) ? (tx * 4 + j) : (64 + tx * 4 + (j - 4));
            float4 lo = {acc[0][j], acc[1][j], acc[2][j], acc[3][j]};
            float4 hi = {acc[4][j], acc[5][j], acc[6][j], acc[7][j]};
            float* dst = base + (size_t)col_g * D + 128 + ty * 8;
            *(float4*)dst       = lo;
            *(float4*)(dst + 4) = hi;
        }
    }
}

// packed-lower-triangle row offset, rows padded to 4 floats
__device__ __forceinline__ int rowoff(int i) {
    int q = i >> 2, s = i & 3;
    return 4 * (2 * q * (q + 1) + s * (q + 1));
}

__device__ __forceinline__ void factor_diag(
    float* T, float (*L11c)[16], float* invdb, int kb16, int lane, float& plog) {
    const int r = kb16 + lane;
    float rr[16];
    const float* Tr = T + rowoff(r);
    #pragma unroll
    for (int q = 0; q < 4; ++q) {
        if (kb16 + q * 4 <= r) {
            float4 v = *(const float4*)(Tr + kb16 + q * 4);
            rr[q*4+0] = v.x; rr[q*4+1] = v.y; rr[q*4+2] = v.z; rr[q*4+3] = v.w;
        } else {
            rr[q*4+0] = 0.0f; rr[q*4+1] = 0.0f; rr[q*4+2] = 0.0f; rr[q*4+3] = 0.0f;
        }
    }
    float mypiv = 1.0f, myinv = 1.0f;
    #pragma unroll
    for (int pc = 0; pc < 16; ++pc) {
        const float piv = __shfl(rr[pc], pc);
        const float inv = 1.0f / sqrtf(piv);
        mypiv = (lane == pc) ? piv : mypiv;
        myinv = (lane == pc) ? inv : myinv;
        if (lane > pc) rr[pc] *= inv;
        #pragma unroll
        for (int j = pc + 1; j < 16; ++j) {
            const float Lj = __shfl(rr[pc], j);
            if (lane >= j) rr[j] = fmaf(-rr[pc], Lj, rr[j]);
        }
    }
    plog += __logf(mypiv);
    invdb[lane] = myinv;
    #pragma unroll
    for (int pp = 0; pp < 16; ++pp)
        if (pp < lane) L11c[pp][lane] = rr[pp];
}

// finalize loss when this is the last of the G chol blocks (device-scope
// counter + threadfence release/acquire; ctr zeroed by k_prefix2 each call).
__device__ void finalize_if_last(const float* ld, const int* counts, const int* need,
                                 float* out, int* ctr) {
    __threadfence();
    const int old = atomicAdd(ctr, 1);
    if (old == G - 1) {
        __threadfence();
        const float min_tcr = 0.5f * logf(256.0f);
        const float log_diag = logf(1.0f + 1e-6f + 1e-12f);
        float s[2] = {0.0f, 0.0f}, c2[2] = {0.0f, 0.0f};
        for (int g = 0; g < G; ++g) {
            if (counts[g] < MINS) continue;
            float def = 0.0f;                   // certified: deficit exactly 0
            if (need[g]) {
                const float nn = fmaxf((float)counts[g], 1.0f);
                const float logdet = ld[g] + (nn - (float)D) * log_diag;
                def = fmaxf(min_tcr - 0.5f * logdet, 0.0f);
            }
            s[g / NC] += def; c2[g / NC] += 1.0f;
        }
        float avg = 0.0f;
        for (int b = 0; b < 2; ++b)
            avg += (c2[b] > 0.0f) ? s[b] / fmaxf(c2[b], 1.0f) : 0.0f;
        out[0] = 0.05f * 0.5f * avg;            // loss_weight*lambda*mean over B=2
    }
}

// fallback blocked Cholesky (sums CH split-K partials inline; early-exits for
// certified groups; last finishing block computes the final loss).
__global__ __launch_bounds__(512) void k_chol(
    const float* __restrict__ part, const int* __restrict__ counts,
    const int* __restrict__ need, float* __restrict__ logdetbuf,
    int* __restrict__ ctr, float* __restrict__ out, int CH) {
    const int g = blockIdx.x;
    const int tid = threadIdx.x;
    if (!need[g]) {
        if (tid == 0) finalize_if_last(logdetbuf, counts, need, out, ctr);
        return;
    }
    __shared__ float T[33280];
    __shared__ float PT[16 * 256];
    __shared__ float L11c[2][16][16];
    __shared__ float invdb[2][16];
    __shared__ int tctr;

    const int n = counts[g];
    const float nn = fmaxf((float)n, 1.0f);
    const float aa = (float)D / (nn * 0.04f);
    const float dg = 1.0f + 1e-6f;

    // load M = a*(sum_ch partial) + (1+1e-6)I into packed triangle (2 thr/row)
    {
        const int r = tid >> 1, half = tid & 1;
        const int nch = (r >> 2) + 1;
        const int mid = (nch + 1) >> 1;
        const int clo = half ? mid : 0;
        const int chi = half ? nch : mid;
        float* Tr = T + rowoff(r);
        for (int c = clo; c < chi; ++c) {
            const float4* p4 = (const float4*)(part + (size_t)g * (D * D) + (size_t)r * D) + c;
            float4 v = *p4;
            for (int ch = 1; ch < CH; ++ch) {
                const float4 t = *(const float4*)((const float*)p4 + (size_t)ch * G * D * D);
                v.x += t.x; v.y += t.y; v.z += t.z; v.w += t.w;
            }
            v.x *= aa; v.y *= aa; v.z *= aa; v.w *= aa;
            v.x += (c * 4 + 0 == r) ? dg : 0.0f;
            v.y += (c * 4 + 1 == r) ? dg : 0.0f;
            v.z += (c * 4 + 2 == r) ? dg : 0.0f;
            v.w += (c * 4 + 3 == r) ? dg : 0.0f;
            *(float4*)(Tr + c * 4) = v;
        }
    }
    __syncthreads();

    float plog = 0.0f;
    const int wave = tid >> 6;
    const int lane = tid & 63;
    const int li = lane >> 3, lj = lane & 7;

    if (tid < 16) factor_diag(T, L11c[0], invdb[0], 0, tid, plog);
    __syncthreads();

    for (int kb = 0; kb < 15; ++kb) {
        const int kb16 = kb * 16;
        const int par = kb & 1;
        const int pstart = kb16 + 16;
        const int R = 256 - pstart;

        if (tid < R) {
            const int r = pstart + tid;
            const float* Tr = T + rowoff(r) + kb16;
            float x[16];
            {
                float4 v0 = *(const float4*)(Tr + 0);
                float4 v1 = *(const float4*)(Tr + 4);
                float4 v2 = *(const float4*)(Tr + 8);
                float4 v3 = *(const float4*)(Tr + 12);
                x[0]=v0.x; x[1]=v0.y; x[2]=v0.z; x[3]=v0.w;
                x[4]=v1.x; x[5]=v1.y; x[6]=v1.z; x[7]=v1.w;
                x[8]=v2.x; x[9]=v2.y; x[10]=v2.z; x[11]=v2.w;
                x[12]=v3.x; x[13]=v3.y; x[14]=v3.z; x[15]=v3.w;
            }
            float iv[16];
            {
                const float* ivp = invdb[par];
                float4 i0 = *(const float4*)(ivp + 0);
                float4 i1 = *(const float4*)(ivp + 4);
                float4 i2 = *(const float4*)(ivp + 8);
                float4 i3 = *(const float4*)(ivp + 12);
                iv[0]=i0.x; iv[1]=i0.y; iv[2]=i0.z; iv[3]=i0.w;
                iv[4]=i1.x; iv[5]=i1.y; iv[6]=i1.z; iv[7]=i1.w;
                iv[8]=i2.x; iv[9]=i2.y; iv[10]=i2.z; iv[11]=i2.w;
                iv[12]=i3.x; iv[13]=i3.y; iv[14]=i3.z; iv[15]=i3.w;
            }
            const float (*Lc)[16] = L11c[par];
            float4 n0 = *(const float4*)&Lc[0][0];
            float4 n1 = *(const float4*)&Lc[0][4];
            float4 n2 = *(const float4*)&Lc[0][8];
            float4 n3 = *(const float4*)&Lc[0][12];
            #pragma unroll
            for (int c = 0; c < 16; ++c) {
                const float col[16] = {n0.x,n0.y,n0.z,n0.w, n1.x,n1.y,n1.z,n1.w,
                                       n2.x,n2.y,n2.z,n2.w, n3.x,n3.y,n3.z,n3.w};
                if (c < 15) {
                    n0 = *(const float4*)&Lc[c+1][0];
                    n1 = *(const float4*)&Lc[c+1][4];
                    n2 = *(const float4*)&Lc[c+1][8];
                    n3 = *(const float4*)&Lc[c+1][12];
                }
                const float xc = x[c] * iv[c];
                x[c] = xc;
                #pragma unroll
                for (int j = 0; j < 16; ++j)
                    if (j > c) x[j] = fmaf(-xc, col[j], x[j]);
            }
            #pragma unroll
            for (int pp = 0; pp < 16; ++pp)
                PT[pp * 256 + r] = x[pp];
        }
        if (tid == 0) tctr = 1;
        __syncthreads();

        const int MRm = (R + 31) >> 5;
        const int nmac = MRm * (MRm + 1) / 2;

        auto do_tile = [&](int idx) {
            int MI = 0, base = 0;
            while (base + MI + 1 <= idx) { base += MI + 1; ++MI; }
            const int MJ = idx - base;
            const int r0 = pstart + MI * 32 + li * 4;
            const int c0 = pstart + MJ * 32 + lj * 4;
            if (r0 >= 256 || c0 >= 256) return;
            if (c0 > r0 + 3) return;
            float acc[4][4];
            #pragma unroll
            for (int qi = 0; qi < 4; ++qi)
                #pragma unroll
                for (int qj = 0; qj < 4; ++qj) acc[qi][qj] = 0.0f;
            #pragma unroll
            for (int pq = 0; pq < 4; ++pq) {
                float4 a[4], b[4];
                #pragma unroll
                for (int q = 0; q < 4; ++q) {
                    a[q] = *(const float4*)&PT[(pq * 4 + q) * 256 + r0];
                    b[q] = *(const float4*)&PT[(pq * 4 + q) * 256 + c0];
                }
                #pragma unroll
                for (int q = 0; q < 4; ++q) {
                    float a4[4] = {a[q].x, a[q].y, a[q].z, a[q].w};
                    float b4[4] = {b[q].x, b[q].y, b[q].z, b[q].w};
                    #pragma unroll
                    for (int qi = 0; qi < 4; ++qi)
                        #pragma unroll
                        for (int qj = 0; qj < 4; ++qj)
                            acc[qi][qj] = fmaf(a4[qi], b4[qj], acc[qi][qj]);
                }
            }
            #pragma unroll
            for (int qi = 0; qi < 4; ++qi) {
                const int r = r0 + qi;
                float* cp = T + rowoff(r) + c0;
                if (c0 + 3 <= r) {
                    float4 t = *(float4*)cp;
                    t.x -= acc[qi][0]; t.y -= acc[qi][1];
                    t.z -= acc[qi][2]; t.w -= acc[qi][3];
                    *(float4*)cp = t;
                } else {
                    #pragma unroll
                    for (int qj = 0; qj < 4; ++qj)
                        if (c0 + qj <= r) cp[qj] -= acc[qi][qj];
                }
            }
        };

        if (wave == 0) {
            do_tile(0);
            if (lane < 16)
                factor_diag(T, L11c[par ^ 1], invdb[par ^ 1], pstart, lane, plog);
        }
        int grab;
        if (lane == 0) grab = atomicAdd(&tctr, 1);
        grab = __shfl(grab, 0);
        while (grab < nmac) {
            do_tile(grab);
            if (lane == 0) grab = atomicAdd(&tctr, 1);
            grab = __shfl(grab, 0);
        }
        __syncthreads();
    }

    if (tid < 16) {
        #pragma unroll
        for (int d = 8; d; d >>= 1) plog += __shfl_xor(plog, d);
        if (tid == 0) logdetbuf[g] = plog;
    }
    if (tid == 0) finalize_if_last(logdetbuf, counts, need, out, ctr);
}

extern "C" void kernel_launch(void* const* d_in, const int* in_sizes, int n_in,
                              void* d_out, int out_size, void* d_ws, size_t ws_size,
                              hipStream_t stream) {
    const int*   target = (const int*)d_in[1];
    const float* feat   = (const float*)d_in[2];
    const int*   batch  = (const int*)d_in[3];
    float* out = (float*)d_out;
    char* ws = (char*)d_ws;
    const int n = in_sizes[1];

    int*   counts = (int*)(ws + OFF_CNT);
    int*   offs   = (int*)(ws + OFF_OFFS);
    float* logdet = (float*)(ws + OFF_LOGDET);
    int*   need   = (int*)(ws + OFF_NEED);
    int*   ctr    = (int*)(ws + OFF_CTR);
    int*   hist   = (int*)(ws + OFF_HIST);
    int*   nzhist = (int*)(ws + OFF_NZH);
    int*   idxbuf = (int*)(ws + OFF_IDX);
    unsigned char* nzflag = (unsigned char*)(ws + OFF_NZF);
    float* rnorm  = (float*)(ws + OFF_RNORM);
    float* part   = (float*)(ws + OFF_GRAM);

    long avail = (long)ws_size - (long)OFF_GRAM;
    long c = avail / (long)GRAM_BYTES;
    const int CH = (int)(c < 1 ? 1 : (c > 8 ? 8 : c));

    const int chunks = (n + 255) / 256;
    const int cpb = (chunks + NBH - 1) / NBH;

    k_norm    <<<(n + 3) / 4, 256, 0, stream>>>(feat, rnorm, nzflag, n);
    k_hist    <<<NBH, 256, 0, stream>>>(target, batch, nzflag, hist, nzhist, n, cpb, chunks);
    k_prefix2 <<<1, 256, 0, stream>>>(hist, nzhist, counts, offs, need, ctr);
    k_scatter2<<<NBH, 256, 0, stream>>>(target, batch, hist, need, idxbuf, n, cpb, chunks);
    k_gram    <<<dim3(3, G, CH), 256, 0, stream>>>(feat, rnorm, idxbuf, counts, offs, need, part);
    k_chol    <<<G, 512, 0, stream>>>(part, counts, need, logdet, ctr, out, CH);
}